// Round 1
// baseline (1466.255 us; speedup 1.0000x reference)
//
#include <hip/hip_runtime.h>

// TransformerModel: 6-layer pre-LN encoder, B=8 S=1024 D=512 H=8 DH=64 FFN=2048.
// Strategy: bf16 MFMA (16x16x32) for all GEMMs and attention, fp32 accumulate.
// Weights transposed+cast to bf16 once per launch into d_ws (~38MB); activations
// flow as bf16 between ops. ws requirement ~= 148 MB.

#define D_MODEL 512
#define DFF 2048
#define SEQ 1024
#define BATCH 8
#define ROWS 8192            // B*S
#define NHEAD 8
#define DHEAD 64

using bf16x8 = __attribute__((ext_vector_type(8))) short;
using f32x4  = __attribute__((ext_vector_type(4))) float;

__device__ __forceinline__ unsigned short f2bf(float f) {
  union { float f; unsigned u; } v; v.f = f;
  unsigned r = v.u + 0x7FFFu + ((v.u >> 16) & 1u);   // RNE
  return (unsigned short)(r >> 16);
}
__device__ __forceinline__ float bf2f(unsigned short b) {
  union { unsigned u; float f; } v; v.u = ((unsigned)b) << 16;
  return v.f;
}

// ---------------------------------------------------------------- transpose+cast
// W (f32, L x K x N, layer = blockIdx.z) -> Wt (bf16, L x N x K)
__global__ __launch_bounds__(256) void transpose_cast_k(
    const float* __restrict__ W, unsigned short* __restrict__ Wt, int K, int N)
{
  __shared__ float tile[32][33];
  const int l = blockIdx.z;
  const float* Wl = W + (size_t)l * K * N;
  unsigned short* Wtl = Wt + (size_t)l * K * N;
  const int k0 = blockIdx.y * 32, n0 = blockIdx.x * 32;
  const int tx = threadIdx.x & 31, ty = threadIdx.x >> 5;
  #pragma unroll
  for (int i = ty; i < 32; i += 8)
    tile[i][tx] = Wl[(size_t)(k0 + i) * N + n0 + tx];
  __syncthreads();
  #pragma unroll
  for (int i = ty; i < 32; i += 8)
    Wtl[(size_t)(n0 + i) * K + k0 + tx] = f2bf(tile[tx][i]);
}

// ---------------------------------------------------------------- layernorm
// x f32 [rows][512] -> y bf16, wave per row
__global__ __launch_bounds__(256) void ln_k(
    const float* __restrict__ x, const float* __restrict__ g,
    const float* __restrict__ be, unsigned short* __restrict__ y, int rows)
{
  const int wid = (blockIdx.x << 2) | (threadIdx.x >> 6);
  const int lane = threadIdx.x & 63;
  if (wid >= rows) return;
  const float4* xr = reinterpret_cast<const float4*>(x + (size_t)wid * D_MODEL);
  float4 a = xr[lane];
  float4 b = xr[lane + 64];
  float s = a.x + a.y + a.z + a.w + b.x + b.y + b.z + b.w;
  #pragma unroll
  for (int m = 32; m >= 1; m >>= 1) s += __shfl_xor(s, m);
  const float mu = s * (1.0f / 512.0f);
  const float d0 = a.x - mu, d1 = a.y - mu, d2 = a.z - mu, d3 = a.w - mu;
  const float e0 = b.x - mu, e1 = b.y - mu, e2 = b.z - mu, e3 = b.w - mu;
  float q = d0*d0 + d1*d1 + d2*d2 + d3*d3 + e0*e0 + e1*e1 + e2*e2 + e3*e3;
  #pragma unroll
  for (int m = 32; m >= 1; m >>= 1) q += __shfl_xor(q, m);
  const float inv = rsqrtf(q * (1.0f / 512.0f) + 1e-3f);
  const float4* gr = reinterpret_cast<const float4*>(g);
  const float4* br = reinterpret_cast<const float4*>(be);
  const float4 g0 = gr[lane], g1 = gr[lane + 64];
  const float4 h0 = br[lane], h1 = br[lane + 64];
  ushort4 o0, o1;
  o0.x = f2bf(d0 * inv * g0.x + h0.x);
  o0.y = f2bf(d1 * inv * g0.y + h0.y);
  o0.z = f2bf(d2 * inv * g0.z + h0.z);
  o0.w = f2bf(d3 * inv * g0.w + h0.w);
  o1.x = f2bf(e0 * inv * g1.x + h1.x);
  o1.y = f2bf(e1 * inv * g1.y + h1.y);
  o1.z = f2bf(e2 * inv * g1.z + h1.z);
  o1.w = f2bf(e3 * inv * g1.w + h1.w);
  *reinterpret_cast<ushort4*>(y + (size_t)wid * D_MODEL + lane * 4) = o0;
  *reinterpret_cast<ushort4*>(y + (size_t)wid * D_MODEL + (lane + 64) * 4) = o1;
}

// ---------------------------------------------------------------- GEMM (bf16 MFMA)
// C[M][N] = A[M][K] @ Wt[N][K]^T  (+bias) (+res) (relu) ; out bf16 or f32
// 64x64 tile, BK=32, 4 waves each 32x32 (2x2 frags of 16x16x32)
template<bool RELU, bool HASBIAS, bool HASRES, bool OUTBF>
__global__ __launch_bounds__(256) void gemm_k(
    const unsigned short* __restrict__ A,
    const unsigned short* __restrict__ Wt,
    const float* __restrict__ bias,
    const float* __restrict__ res,
    void* __restrict__ outp, int M, int N, int K)
{
  __shared__ unsigned short As[64][40];   // pad to 40 bf16 (80B rows, 16B-aligned)
  __shared__ unsigned short Bs[64][40];
  const int t = threadIdx.x;
  const int m0 = blockIdx.y * 64, n0 = blockIdx.x * 64;
  const int w = t >> 6, lane = t & 63;
  const int wr = w >> 1, wc = w & 1;
  const int lhi = lane >> 4, llo = lane & 15;
  const int lrow = t >> 2, lcol = (t & 3) * 8;

  f32x4 acc[2][2] = {};

  for (int k0 = 0; k0 < K; k0 += 32) {
    __syncthreads();
    *reinterpret_cast<uint4*>(&As[lrow][lcol]) =
        *reinterpret_cast<const uint4*>(&A[(size_t)(m0 + lrow) * K + k0 + lcol]);
    *reinterpret_cast<uint4*>(&Bs[lrow][lcol]) =
        *reinterpret_cast<const uint4*>(&Wt[(size_t)(n0 + lrow) * K + k0 + lcol]);
    __syncthreads();
    bf16x8 af0 = *reinterpret_cast<const bf16x8*>(&As[wr * 32 + llo][lhi * 8]);
    bf16x8 af1 = *reinterpret_cast<const bf16x8*>(&As[wr * 32 + 16 + llo][lhi * 8]);
    bf16x8 bf0 = *reinterpret_cast<const bf16x8*>(&Bs[wc * 32 + llo][lhi * 8]);
    bf16x8 bf1 = *reinterpret_cast<const bf16x8*>(&Bs[wc * 32 + 16 + llo][lhi * 8]);
    acc[0][0] = __builtin_amdgcn_mfma_f32_16x16x32_bf16(af0, bf0, acc[0][0], 0, 0, 0);
    acc[0][1] = __builtin_amdgcn_mfma_f32_16x16x32_bf16(af0, bf1, acc[0][1], 0, 0, 0);
    acc[1][0] = __builtin_amdgcn_mfma_f32_16x16x32_bf16(af1, bf0, acc[1][0], 0, 0, 0);
    acc[1][1] = __builtin_amdgcn_mfma_f32_16x16x32_bf16(af1, bf1, acc[1][1], 0, 0, 0);
  }

  #pragma unroll
  for (int fi = 0; fi < 2; fi++)
    #pragma unroll
    for (int fj = 0; fj < 2; fj++)
      #pragma unroll
      for (int i = 0; i < 4; i++) {
        const int row = m0 + wr * 32 + fi * 16 + lhi * 4 + i;
        const int col = n0 + wc * 32 + fj * 16 + llo;
        float v = acc[fi][fj][i];
        if (HASBIAS) v += bias[col];
        if (HASRES)  v += res[(size_t)row * N + col];
        if (RELU)    v = fmaxf(v, 0.0f);
        if (OUTBF) ((unsigned short*)outp)[(size_t)row * N + col] = f2bf(v);
        else       ((float*)outp)[(size_t)row * N + col] = v;
      }
}

// ---------------------------------------------------------------- attention
// Flash attention, block = (qtile 64 rows, head, batch), 4 waves x 16 q-rows.
// Q/K staged bf16 in LDS [row][d]; V staged transposed [d][kv]; QK^T and PV via
// MFMA; online softmax on C-layout registers.
__global__ __launch_bounds__(256) void attn_k(
    const unsigned short* __restrict__ Qb,
    const unsigned short* __restrict__ Kb,
    const unsigned short* __restrict__ Vb,
    unsigned short* __restrict__ Zb)
{
  __shared__ unsigned short Qs[64][72];
  __shared__ unsigned short Ks[64][72];
  __shared__ unsigned short VsT[64][72];   // VsT[dv][kv]
  __shared__ unsigned short Ps[4][16][72]; // per-wave P rows (bf16)

  const int t = threadIdx.x;
  const int qt = blockIdx.x, h = blockIdx.y, bb = blockIdx.z;
  const size_t baserow = (size_t)bb * SEQ;
  const int colbase = h * DHEAD;
  const int w = t >> 6, lane = t & 63, lhi = lane >> 4, llo = lane & 15;
  const int r = t >> 2, c0 = (t & 3) * 16;

  // stage Q (scaled by 1/sqrt(64) = 0.125, exact in bf16)
  {
    const unsigned short* src = Qb + (baserow + qt * 64 + r) * D_MODEL + colbase + c0;
    uint4 u0 = *reinterpret_cast<const uint4*>(src);
    uint4 u1 = *reinterpret_cast<const uint4*>(src + 8);
    unsigned a_[8] = {u0.x, u0.y, u0.z, u0.w, u1.x, u1.y, u1.z, u1.w};
    #pragma unroll
    for (int j = 0; j < 8; j++) {
      unsigned lo = f2bf(bf2f((unsigned short)(a_[j] & 0xffffu)) * 0.125f);
      unsigned hi = f2bf(bf2f((unsigned short)(a_[j] >> 16)) * 0.125f);
      a_[j] = lo | (hi << 16);
    }
    uint4 p0; p0.x = a_[0]; p0.y = a_[1]; p0.z = a_[2]; p0.w = a_[3];
    uint4 p1; p1.x = a_[4]; p1.y = a_[5]; p1.z = a_[6]; p1.w = a_[7];
    *reinterpret_cast<uint4*>(&Qs[r][c0]) = p0;
    *reinterpret_cast<uint4*>(&Qs[r][c0 + 8]) = p1;
  }

  float m_[4], l_[4];
  f32x4 o_[4] = {};
  #pragma unroll
  for (int i = 0; i < 4; i++) { m_[i] = -1e30f; l_[i] = 0.0f; }

  for (int kt = 0; kt < 16; kt++) {
    __syncthreads();   // previous tile's reads complete
    // stage K tile
    {
      const unsigned short* src = Kb + (baserow + kt * 64 + r) * D_MODEL + colbase + c0;
      *reinterpret_cast<uint4*>(&Ks[r][c0]) = *reinterpret_cast<const uint4*>(src);
      *reinterpret_cast<uint4*>(&Ks[r][c0 + 8]) = *reinterpret_cast<const uint4*>(src + 8);
    }
    // stage V tile transposed
    {
      const unsigned short* src = Vb + (baserow + kt * 64 + r) * D_MODEL + colbase + c0;
      uint4 u0 = *reinterpret_cast<const uint4*>(src);
      uint4 u1 = *reinterpret_cast<const uint4*>(src + 8);
      unsigned a_[8] = {u0.x, u0.y, u0.z, u0.w, u1.x, u1.y, u1.z, u1.w};
      #pragma unroll
      for (int j = 0; j < 8; j++) {
        VsT[c0 + 2 * j][r]     = (unsigned short)(a_[j] & 0xffffu);
        VsT[c0 + 2 * j + 1][r] = (unsigned short)(a_[j] >> 16);
      }
    }
    __syncthreads();

    // ---- QK^T : S[16 q][64 kc] per wave
    f32x4 s_[4] = {};
    #pragma unroll
    for (int ds = 0; ds < 2; ds++) {
      bf16x8 aq = *reinterpret_cast<const bf16x8*>(&Qs[w * 16 + llo][ds * 32 + lhi * 8]);
      #pragma unroll
      for (int fj = 0; fj < 4; fj++) {
        bf16x8 bk = *reinterpret_cast<const bf16x8*>(&Ks[fj * 16 + llo][ds * 32 + lhi * 8]);
        s_[fj] = __builtin_amdgcn_mfma_f32_16x16x32_bf16(aq, bk, s_[fj], 0, 0, 0);
      }
    }

    // ---- online softmax (rows live at lhi*4+i, cols at fj*16+llo)
    float alpha[4];
    #pragma unroll
    for (int i = 0; i < 4; i++) {
      float tm = fmaxf(fmaxf(s_[0][i], s_[1][i]), fmaxf(s_[2][i], s_[3][i]));
      tm = fmaxf(tm, __shfl_xor(tm, 1));
      tm = fmaxf(tm, __shfl_xor(tm, 2));
      tm = fmaxf(tm, __shfl_xor(tm, 4));
      tm = fmaxf(tm, __shfl_xor(tm, 8));
      const float mn = fmaxf(m_[i], tm);
      alpha[i] = __expf(m_[i] - mn);
      float ps = 0.0f;
      #pragma unroll
      for (int fj = 0; fj < 4; fj++) {
        const float p = __expf(s_[fj][i] - mn);
        ps += p;
        Ps[w][lhi * 4 + i][fj * 16 + llo] = f2bf(p);
      }
      ps += __shfl_xor(ps, 1);
      ps += __shfl_xor(ps, 2);
      ps += __shfl_xor(ps, 4);
      ps += __shfl_xor(ps, 8);
      l_[i] = l_[i] * alpha[i] + ps;
      m_[i] = mn;
    }
    #pragma unroll
    for (int fo = 0; fo < 4; fo++)
      #pragma unroll
      for (int i = 0; i < 4; i++) o_[fo][i] *= alpha[i];

    // ---- PV : O[16 q][64 dv] += P @ V   (Ps per-wave private; in-wave ordering ok)
    #pragma unroll
    for (int ks = 0; ks < 2; ks++) {
      bf16x8 ap = *reinterpret_cast<const bf16x8*>(&Ps[w][llo][ks * 32 + lhi * 8]);
      #pragma unroll
      for (int fo = 0; fo < 4; fo++) {
        bf16x8 bv = *reinterpret_cast<const bf16x8*>(&VsT[fo * 16 + llo][ks * 32 + lhi * 8]);
        o_[fo] = __builtin_amdgcn_mfma_f32_16x16x32_bf16(ap, bv, o_[fo], 0, 0, 0);
      }
    }
  }

  // ---- finalize + write z (bf16)
  #pragma unroll
  for (int fo = 0; fo < 4; fo++)
    #pragma unroll
    for (int i = 0; i < 4; i++) {
      const float v = o_[fo][i] / l_[i];
      const size_t row = baserow + qt * 64 + w * 16 + lhi * 4 + i;
      Zb[row * D_MODEL + colbase + fo * 16 + llo] = f2bf(v);
    }
}

// ---------------------------------------------------------------- driver
extern "C" void kernel_launch(void* const* d_in, const int* in_sizes, int n_in,
                              void* d_out, int out_size, void* d_ws, size_t ws_size,
                              hipStream_t stream)
{
  const float* x   = (const float*)d_in[0];
  const float* Wq  = (const float*)d_in[1];
  const float* Wk  = (const float*)d_in[2];
  const float* Wv  = (const float*)d_in[3];
  const float* Wo  = (const float*)d_in[4];
  const float* W1  = (const float*)d_in[5];
  const float* b1  = (const float*)d_in[6];
  const float* W2  = (const float*)d_in[7];
  const float* b2  = (const float*)d_in[8];
  const float* ga  = (const float*)d_in[9];
  const float* ba  = (const float*)d_in[10];
  const float* gf  = (const float*)d_in[11];
  const float* bfn = (const float*)d_in[12];
  float* out = (float*)d_out;

  char* p = (char*)d_ws;
  auto alloc = [&](size_t bytes) { void* r = (void*)p; p += (bytes + 255) & ~(size_t)255; return r; };
  float* E0 = (float*)alloc((size_t)ROWS * D_MODEL * 4);
  float* E1 = (float*)alloc((size_t)ROWS * D_MODEL * 4);
  unsigned short* Ybf  = (unsigned short*)alloc((size_t)ROWS * D_MODEL * 2);
  unsigned short* Qbf  = (unsigned short*)alloc((size_t)ROWS * D_MODEL * 2);
  unsigned short* Kbf  = (unsigned short*)alloc((size_t)ROWS * D_MODEL * 2);
  unsigned short* Vbf  = (unsigned short*)alloc((size_t)ROWS * D_MODEL * 2);
  unsigned short* Zbf  = (unsigned short*)alloc((size_t)ROWS * D_MODEL * 2);
  unsigned short* H1bf = (unsigned short*)alloc((size_t)ROWS * DFF * 2);
  unsigned short* WtQ = (unsigned short*)alloc(6ull * 512 * 512 * 2);
  unsigned short* WtK = (unsigned short*)alloc(6ull * 512 * 512 * 2);
  unsigned short* WtV = (unsigned short*)alloc(6ull * 512 * 512 * 2);
  unsigned short* WtO = (unsigned short*)alloc(6ull * 512 * 512 * 2);
  unsigned short* Wt1 = (unsigned short*)alloc(6ull * 512 * 2048 * 2);
  unsigned short* Wt2 = (unsigned short*)alloc(6ull * 2048 * 512 * 2);

  // one-time weight transpose+cast (runs each call; ~25us)
  transpose_cast_k<<<dim3(16, 16, 6), 256, 0, stream>>>(Wq, WtQ, 512, 512);
  transpose_cast_k<<<dim3(16, 16, 6), 256, 0, stream>>>(Wk, WtK, 512, 512);
  transpose_cast_k<<<dim3(16, 16, 6), 256, 0, stream>>>(Wv, WtV, 512, 512);
  transpose_cast_k<<<dim3(16, 16, 6), 256, 0, stream>>>(Wo, WtO, 512, 512);
  transpose_cast_k<<<dim3(64, 16, 6), 256, 0, stream>>>(W1, Wt1, 512, 2048);
  transpose_cast_k<<<dim3(16, 64, 6), 256, 0, stream>>>(W2, Wt2, 2048, 512);

  for (int l = 0; l < 6; l++) {
    const float* enc = (l == 0) ? x : E0;
    // pre-LN attention
    ln_k<<<2048, 256, 0, stream>>>(enc, ga + l * 512, ba + l * 512, Ybf, ROWS);
    gemm_k<false, false, false, true><<<dim3(8, 128), 256, 0, stream>>>(
        Ybf, WtQ + (size_t)l * 262144, nullptr, nullptr, Qbf, ROWS, 512, 512);
    gemm_k<false, false, false, true><<<dim3(8, 128), 256, 0, stream>>>(
        Ybf, WtK + (size_t)l * 262144, nullptr, nullptr, Kbf, ROWS, 512, 512);
    gemm_k<false, false, false, true><<<dim3(8, 128), 256, 0, stream>>>(
        Ybf, WtV + (size_t)l * 262144, nullptr, nullptr, Vbf, ROWS, 512, 512);
    attn_k<<<dim3(16, 8, 8), 256, 0, stream>>>(Qbf, Kbf, Vbf, Zbf);
    gemm_k<false, false, true, false><<<dim3(8, 128), 256, 0, stream>>>(
        Zbf, WtO + (size_t)l * 262144, nullptr, enc, E1, ROWS, 512, 512);
    // pre-LN FFN
    ln_k<<<2048, 256, 0, stream>>>(E1, gf + l * 512, bfn + l * 512, Ybf, ROWS);
    gemm_k<true, true, false, true><<<dim3(32, 128), 256, 0, stream>>>(
        Ybf, Wt1 + (size_t)l * 1048576, b1 + l * 2048, nullptr, H1bf, ROWS, 2048, 512);
    gemm_k<false, true, true, false><<<dim3(8, 128), 256, 0, stream>>>(
        H1bf, Wt2 + (size_t)l * 1048576, b2 + l * 512, E1, (l == 5) ? out : E0,
        ROWS, 512, 2048);
  }
}

// Round 2
// 1286.388 us; speedup vs baseline: 1.1398x; 1.1398x over previous
//
#include <hip/hip_runtime.h>

// 6-layer pre-LN encoder, B=8 S=1024 D=512 H=8 DH=64 FFN=2048.
// Round 2: m97-style 128x128 GEMM w/ global_load_lds(16B); fused QKV GEMM;
// attention with frag-major LDS staging via pre-swizzled global sources.

#define SEQ 1024
#define ROWS 8192
#define QKVW 1536

using bf16x8 = __attribute__((ext_vector_type(8))) short;
using f32x4  = __attribute__((ext_vector_type(4))) float;

__device__ __forceinline__ unsigned short f2bf(float f) {
  union { float f; unsigned u; } v; v.f = f;
  unsigned r = v.u + 0x7FFFu + ((v.u >> 16) & 1u);   // RNE
  return (unsigned short)(r >> 16);
}

__device__ __forceinline__ void gl16(const void* g, void* l) {
  typedef const unsigned int __attribute__((address_space(1)))* GP;
  typedef unsigned int __attribute__((address_space(3)))* LP;
  __builtin_amdgcn_global_load_lds((GP)g, (LP)l, 16, 0, 0);
}

// ---------------------------------------------------------------- weight prep
// W (f32, [L][K][N]) -> Wt (bf16, [l*lstride + n*K + k]) with optional scale
__global__ __launch_bounds__(256) void transpose_cast_k(
    const float* __restrict__ W, unsigned short* __restrict__ Wt,
    int K, int N, int lstride, float scale)
{
  __shared__ float tile[32][33];
  const int l = blockIdx.z;
  const float* Wl = W + (size_t)l * K * N;
  unsigned short* Wtl = Wt + (size_t)l * lstride;
  const int k0 = blockIdx.y * 32, n0 = blockIdx.x * 32;
  const int tx = threadIdx.x & 31, ty = threadIdx.x >> 5;
  #pragma unroll
  for (int i = ty; i < 32; i += 8)
    tile[i][tx] = Wl[(size_t)(k0 + i) * N + n0 + tx];
  __syncthreads();
  #pragma unroll
  for (int i = ty; i < 32; i += 8)
    Wtl[(size_t)(n0 + i) * K + k0 + tx] = f2bf(tile[tx][i] * scale);
}

// ---------------------------------------------------------------- layernorm
__global__ __launch_bounds__(256) void ln_k(
    const float* __restrict__ x, const float* __restrict__ g,
    const float* __restrict__ be, unsigned short* __restrict__ y, int rows)
{
  const int wid = (blockIdx.x << 2) | (threadIdx.x >> 6);
  const int lane = threadIdx.x & 63;
  if (wid >= rows) return;
  const float4* xr = reinterpret_cast<const float4*>(x + (size_t)wid * 512);
  float4 a = xr[lane];
  float4 b = xr[lane + 64];
  float s = a.x + a.y + a.z + a.w + b.x + b.y + b.z + b.w;
  #pragma unroll
  for (int m = 32; m >= 1; m >>= 1) s += __shfl_xor(s, m);
  const float mu = s * (1.0f / 512.0f);
  const float d0 = a.x - mu, d1 = a.y - mu, d2 = a.z - mu, d3 = a.w - mu;
  const float e0 = b.x - mu, e1 = b.y - mu, e2 = b.z - mu, e3 = b.w - mu;
  float q = d0*d0 + d1*d1 + d2*d2 + d3*d3 + e0*e0 + e1*e1 + e2*e2 + e3*e3;
  #pragma unroll
  for (int m = 32; m >= 1; m >>= 1) q += __shfl_xor(q, m);
  const float inv = rsqrtf(q * (1.0f / 512.0f) + 1e-3f);
  const float4* gr = reinterpret_cast<const float4*>(g);
  const float4* br = reinterpret_cast<const float4*>(be);
  const float4 g0 = gr[lane], g1 = gr[lane + 64];
  const float4 h0 = br[lane], h1 = br[lane + 64];
  ushort4 o0, o1;
  o0.x = f2bf(d0 * inv * g0.x + h0.x);
  o0.y = f2bf(d1 * inv * g0.y + h0.y);
  o0.z = f2bf(d2 * inv * g0.z + h0.z);
  o0.w = f2bf(d3 * inv * g0.w + h0.w);
  o1.x = f2bf(e0 * inv * g1.x + h1.x);
  o1.y = f2bf(e1 * inv * g1.y + h1.y);
  o1.z = f2bf(e2 * inv * g1.z + h1.z);
  o1.w = f2bf(e3 * inv * g1.w + h1.w);
  *reinterpret_cast<ushort4*>(y + (size_t)wid * 512 + lane * 4) = o0;
  *reinterpret_cast<ushort4*>(y + (size_t)wid * 512 + (lane + 64) * 4) = o1;
}

// ---------------------------------------------------------------- GEMM 128x128 (m97 structure)
// C[M][N] = A[M][K] @ Wt[N][K]^T (+bias)(+res)(relu); 4 waves, each 64x64.
template<bool RELU, bool HASBIAS, bool HASRES, bool OUTBF>
__global__ __launch_bounds__(256) void gemm128_k(
    const unsigned short* __restrict__ A,
    const unsigned short* __restrict__ Wt,
    const float* __restrict__ bias,
    const float* __restrict__ res,
    void* __restrict__ outp, int M, int N, int K)
{
  __shared__ __align__(16) unsigned short As[4096];   // [128][32] linear
  __shared__ __align__(16) unsigned short Bs[4096];
  const int t = threadIdx.x;
  const int m0 = blockIdx.y * 128, n0 = blockIdx.x * 128;
  const int w = t >> 6, lane = t & 63, llo = lane & 15, lhi = lane >> 4;
  const int wr = w >> 1, wc = w & 1;

  // staging: chunk t covers As[t*8 .. t*8+7] = row (t>>2), cols (t&3)*8..+8
  const int sr = t >> 2, sc = (t & 3) * 8;
  const unsigned short* pa0 = &A[(size_t)(m0 + sr) * K + sc];
  const unsigned short* pa1 = &A[(size_t)(m0 + 64 + sr) * K + sc];
  const unsigned short* pb0 = &Wt[(size_t)(n0 + sr) * K + sc];
  const unsigned short* pb1 = &Wt[(size_t)(n0 + 64 + sr) * K + sc];
  unsigned short* la0 = &As[t * 8];
  unsigned short* la1 = &As[2048 + t * 8];
  unsigned short* lb0 = &Bs[t * 8];
  unsigned short* lb1 = &Bs[2048 + t * 8];

  f32x4 acc[4][4] = {};
  for (int k0 = 0; k0 < K; k0 += 32) {
    __syncthreads();
    gl16(pa0, la0); gl16(pa1, la1);
    gl16(pb0, lb0); gl16(pb1, lb1);
    pa0 += 32; pa1 += 32; pb0 += 32; pb1 += 32;
    __syncthreads();
    bf16x8 af[4], bfr[4];
    #pragma unroll
    for (int f = 0; f < 4; f++) {
      af[f]  = *reinterpret_cast<const bf16x8*>(&As[(wr * 64 + f * 16 + llo) * 32 + lhi * 8]);
      bfr[f] = *reinterpret_cast<const bf16x8*>(&Bs[(wc * 64 + f * 16 + llo) * 32 + lhi * 8]);
    }
    #pragma unroll
    for (int fi = 0; fi < 4; fi++)
      #pragma unroll
      for (int fj = 0; fj < 4; fj++)
        acc[fi][fj] = __builtin_amdgcn_mfma_f32_16x16x32_bf16(af[fi], bfr[fj], acc[fi][fj], 0, 0, 0);
  }

  const int row0 = m0 + wr * 64, col0 = n0 + wc * 64;
  #pragma unroll
  for (int fi = 0; fi < 4; fi++)
    #pragma unroll
    for (int fj = 0; fj < 4; fj++)
      #pragma unroll
      for (int i = 0; i < 4; i++) {
        const int row = row0 + fi * 16 + lhi * 4 + i;
        const int col = col0 + fj * 16 + llo;
        float v = acc[fi][fj][i];
        if (HASBIAS) v += bias[col];
        if (HASRES)  v += res[(size_t)row * N + col];
        if (RELU)    v = fmaxf(v, 0.0f);
        if (OUTBF) ((unsigned short*)outp)[(size_t)row * N + col] = f2bf(v);
        else       ((float*)outp)[(size_t)row * N + col] = v;
      }
}

// ---------------------------------------------------------------- V transpose
// QKV V-section [8192][1536]@+1024 -> VT [bh][dv 64][s 1024]
__global__ __launch_bounds__(256) void vtrans_k(
    const unsigned short* __restrict__ QKV, unsigned short* __restrict__ VT)
{
  __shared__ unsigned short tile[64][66];
  const int kt = blockIdx.x, bh = blockIdx.y;
  const int bb = bh >> 3, h = bh & 7;
  const int t = threadIdx.x;
  const int r = t >> 2, c0 = (t & 3) * 16;
  const unsigned short* src = &QKV[((size_t)bb * SEQ + kt * 64 + r) * QKVW + 1024 + h * 64 + c0];
  *reinterpret_cast<uint4*>(&tile[r][c0])     = *reinterpret_cast<const uint4*>(src);
  *reinterpret_cast<uint4*>(&tile[r][c0 + 8]) = *reinterpret_cast<const uint4*>(src + 8);
  __syncthreads();
  const int dv = t >> 2, kv0 = (t & 3) * 16;
  ushort4 o0, o1;
  unsigned short tmp[16];
  #pragma unroll
  for (int j = 0; j < 16; j++) tmp[j] = tile[kv0 + j][dv];
  o0.x = tmp[0]; o0.y = tmp[1]; o0.z = tmp[2]; o0.w = tmp[3];
  o1.x = tmp[4]; o1.y = tmp[5]; o1.z = tmp[6]; o1.w = tmp[7];
  ushort4 o2, o3;
  o2.x = tmp[8];  o2.y = tmp[9];  o2.z = tmp[10]; o2.w = tmp[11];
  o3.x = tmp[12]; o3.y = tmp[13]; o3.z = tmp[14]; o3.w = tmp[15];
  unsigned short* dst = &VT[((size_t)bh * 64 + dv) * SEQ + kt * 64 + kv0];
  *reinterpret_cast<ushort4*>(dst)      = o0;
  *reinterpret_cast<ushort4*>(dst + 4)  = o1;
  *reinterpret_cast<ushort4*>(dst + 8)  = o2;
  *reinterpret_cast<ushort4*>(dst + 12) = o3;
}

// ---------------------------------------------------------------- attention
// block = (qt 0..7, h, b); 4 waves x 32 q-rows; kv tiles of 64.
// K and V^T staged frag-major via global_load_lds (pre-swizzled global srcs):
// chunk ((fj*2+ds)*64 + lane) holds frag element [fj*16+(lane&15)][ds*32+(lane>>4)*8 ..+8].
__global__ __launch_bounds__(256) void attn_k(
    const unsigned short* __restrict__ QKV,   // [8192][1536]; Q pre-scaled by 0.125
    const unsigned short* __restrict__ VT,    // [bh][64][1024]
    unsigned short* __restrict__ Zb)          // [8192][512]
{
  __shared__ __align__(16) unsigned short Ks[4096];
  __shared__ __align__(16) unsigned short Vs[4096];
  __shared__ __align__(16) unsigned short Ps[8192];   // 4 waves x 2048

  const int t = threadIdx.x;
  const int qt = blockIdx.x, h = blockIdx.y, bb = blockIdx.z;
  const int w = t >> 6, lane = t & 63, llo = lane & 15, lhi = lane >> 4;
  const size_t rowb = (size_t)bb * SEQ;
  const int kcol = 512 + h * 64;
  const size_t vtb = (size_t)(bb * 8 + h) * 64 * SEQ;

  // hoist Q fragments into registers (scale folded into Wq)
  bf16x8 aq[2][2];
  #pragma unroll
  for (int m = 0; m < 2; m++)
    #pragma unroll
    for (int ds = 0; ds < 2; ds++)
      aq[m][ds] = *reinterpret_cast<const bf16x8*>(
          &QKV[(rowb + qt * 128 + w * 32 + m * 16 + llo) * QKVW + h * 64 + ds * 32 + lhi * 8]);

  // per-issue staging source pointers (chunk c = iss*256 + t)
  const int cA = t, cB = 256 + t;
  const int gA = cA >> 6, lA = cA & 63, gB = cB >> 6, lB = cB & 63;
  const unsigned short* kpA = &QKV[(rowb + (gA >> 1) * 16 + (lA & 15)) * QKVW + kcol + (gA & 1) * 32 + (lA >> 4) * 8];
  const unsigned short* kpB = &QKV[(rowb + (gB >> 1) * 16 + (lB & 15)) * QKVW + kcol + (gB & 1) * 32 + (lB >> 4) * 8];
  const unsigned short* vpA = &VT[vtb + (size_t)((gA >> 1) * 16 + (lA & 15)) * SEQ + (gA & 1) * 32 + (lA >> 4) * 8];
  const unsigned short* vpB = &VT[vtb + (size_t)((gB >> 1) * 16 + (lB & 15)) * SEQ + (gB & 1) * 32 + (lB >> 4) * 8];
  unsigned short* lkA = &Ks[cA * 8];
  unsigned short* lkB = &Ks[cB * 8];
  unsigned short* lvA = &Vs[cA * 8];
  unsigned short* lvB = &Vs[cB * 8];

  float m_[2][4], l_[2][4];
  f32x4 o_[2][4] = {};
  #pragma unroll
  for (int mi = 0; mi < 2; mi++)
    #pragma unroll
    for (int i = 0; i < 4; i++) { m_[mi][i] = -1e30f; l_[mi][i] = 0.0f; }

  const int pw = w * 2048 + ((llo >> 3)) * 128 + lhi * 32 + (llo & 7);

  for (int kt = 0; kt < 16; kt++) {
    __syncthreads();
    gl16(kpA + (size_t)kt * 64 * QKVW, lkA);
    gl16(kpB + (size_t)kt * 64 * QKVW, lkB);
    gl16(vpA + kt * 64, lvA);
    gl16(vpB + kt * 64, lvB);
    __syncthreads();

    // QK^T: S[q 32][kv 64] per wave
    f32x4 s_[2][4] = {};
    #pragma unroll
    for (int ds = 0; ds < 2; ds++)
      #pragma unroll
      for (int fj = 0; fj < 4; fj++) {
        bf16x8 bk = *reinterpret_cast<const bf16x8*>(&Ks[((fj * 2 + ds) * 64 + lane) * 8]);
        s_[0][fj] = __builtin_amdgcn_mfma_f32_16x16x32_bf16(aq[0][ds], bk, s_[0][fj], 0, 0, 0);
        s_[1][fj] = __builtin_amdgcn_mfma_f32_16x16x32_bf16(aq[1][ds], bk, s_[1][fj], 0, 0, 0);
      }

    // online softmax rows (mi, lhi*4+i); cols fj*16+llo
    #pragma unroll
    for (int mi = 0; mi < 2; mi++) {
      #pragma unroll
      for (int i = 0; i < 4; i++) {
        float tm = fmaxf(fmaxf(s_[mi][0][i], s_[mi][1][i]), fmaxf(s_[mi][2][i], s_[mi][3][i]));
        tm = fmaxf(tm, __shfl_xor(tm, 1));
        tm = fmaxf(tm, __shfl_xor(tm, 2));
        tm = fmaxf(tm, __shfl_xor(tm, 4));
        tm = fmaxf(tm, __shfl_xor(tm, 8));
        const float mn = fmaxf(m_[mi][i], tm);
        const float al = __expf(m_[mi][i] - mn);
        float ps = 0.0f;
        #pragma unroll
        for (int fj = 0; fj < 4; fj++) {
          const float p = __expf(s_[mi][fj][i] - mn);
          ps += p;
          Ps[pw + mi * 1024 + (fj >> 1) * 512 + (fj & 1) * 256 + i * 8] = f2bf(p);
        }
        ps += __shfl_xor(ps, 1);
        ps += __shfl_xor(ps, 2);
        ps += __shfl_xor(ps, 4);
        ps += __shfl_xor(ps, 8);
        l_[mi][i] = l_[mi][i] * al + ps;
        m_[mi][i] = mn;
        #pragma unroll
        for (int fo = 0; fo < 4; fo++) o_[mi][fo][i] *= al;
      }
    }

    // PV: O[q 32][dv 64] += P @ V
    #pragma unroll
    for (int ks = 0; ks < 2; ks++) {
      bf16x8 ap0 = *reinterpret_cast<const bf16x8*>(&Ps[w * 2048 + (ks * 64 + lane) * 8]);
      bf16x8 ap1 = *reinterpret_cast<const bf16x8*>(&Ps[w * 2048 + ((2 + ks) * 64 + lane) * 8]);
      #pragma unroll
      for (int fo = 0; fo < 4; fo++) {
        bf16x8 bv = *reinterpret_cast<const bf16x8*>(&Vs[((fo * 2 + ks) * 64 + lane) * 8]);
        o_[0][fo] = __builtin_amdgcn_mfma_f32_16x16x32_bf16(ap0, bv, o_[0][fo], 0, 0, 0);
        o_[1][fo] = __builtin_amdgcn_mfma_f32_16x16x32_bf16(ap1, bv, o_[1][fo], 0, 0, 0);
      }
    }
  }

  #pragma unroll
  for (int mi = 0; mi < 2; mi++)
    #pragma unroll
    for (int fo = 0; fo < 4; fo++)
      #pragma unroll
      for (int i = 0; i < 4; i++) {
        const float v = o_[mi][fo][i] / l_[mi][i];
        Zb[(rowb + qt * 128 + w * 32 + mi * 16 + lhi * 4 + i) * 512 + h * 64 + fo * 16 + llo] = f2bf(v);
      }
}

// ---------------------------------------------------------------- driver
extern "C" void kernel_launch(void* const* d_in, const int* in_sizes, int n_in,
                              void* d_out, int out_size, void* d_ws, size_t ws_size,
                              hipStream_t stream)
{
  const float* x   = (const float*)d_in[0];
  const float* Wq  = (const float*)d_in[1];
  const float* Wk  = (const float*)d_in[2];
  const float* Wv  = (const float*)d_in[3];
  const float* Wo  = (const float*)d_in[4];
  const float* W1  = (const float*)d_in[5];
  const float* b1  = (const float*)d_in[6];
  const float* W2  = (const float*)d_in[7];
  const float* b2  = (const float*)d_in[8];
  const float* ga  = (const float*)d_in[9];
  const float* ba  = (const float*)d_in[10];
  const float* gf  = (const float*)d_in[11];
  const float* bfn = (const float*)d_in[12];
  float* out = (float*)d_out;

  char* p = (char*)d_ws;
  auto alloc = [&](size_t bytes) { void* r = (void*)p; p += (bytes + 255) & ~(size_t)255; return r; };
  float* E0 = (float*)alloc((size_t)ROWS * 512 * 4);
  float* E1 = (float*)alloc((size_t)ROWS * 512 * 4);
  unsigned short* Ybf   = (unsigned short*)alloc((size_t)ROWS * 512 * 2);   // aliased: LN out / attn Z
  unsigned short* QKVbf = (unsigned short*)alloc((size_t)ROWS * QKVW * 2);
  unsigned short* H1bf  = (unsigned short*)alloc((size_t)ROWS * 2048 * 2);  // VT aliases front 8MB
  unsigned short* VT    = H1bf;
  unsigned short* WtQKV = (unsigned short*)alloc(6ull * QKVW * 512 * 2);
  unsigned short* WtO   = (unsigned short*)alloc(6ull * 512 * 512 * 2);
  unsigned short* Wt1   = (unsigned short*)alloc(6ull * 2048 * 512 * 2);
  unsigned short* Wt2   = (unsigned short*)alloc(6ull * 512 * 2048 * 2);
  unsigned short* Zbf   = Ybf;

  // weight prep (Wq scaled by softmax 1/sqrt(DH)=0.125)
  transpose_cast_k<<<dim3(16, 16, 6), 256, 0, stream>>>(Wq, WtQKV,          512, 512,  QKVW * 512, 0.125f);
  transpose_cast_k<<<dim3(16, 16, 6), 256, 0, stream>>>(Wk, WtQKV + 262144, 512, 512,  QKVW * 512, 1.0f);
  transpose_cast_k<<<dim3(16, 16, 6), 256, 0, stream>>>(Wv, WtQKV + 524288, 512, 512,  QKVW * 512, 1.0f);
  transpose_cast_k<<<dim3(16, 16, 6), 256, 0, stream>>>(Wo, WtO,            512, 512,  262144,     1.0f);
  transpose_cast_k<<<dim3(64, 16, 6), 256, 0, stream>>>(W1, Wt1,            512, 2048, 1048576,    1.0f);
  transpose_cast_k<<<dim3(16, 64, 6), 256, 0, stream>>>(W2, Wt2,            2048, 512, 1048576,    1.0f);

  for (int l = 0; l < 6; l++) {
    const float* enc = (l == 0) ? x : E0;
    // pre-LN attention
    ln_k<<<2048, 256, 0, stream>>>(enc, ga + l * 512, ba + l * 512, Ybf, ROWS);
    gemm128_k<false, false, false, true><<<dim3(12, 64), 256, 0, stream>>>(
        Ybf, WtQKV + (size_t)l * QKVW * 512, nullptr, nullptr, QKVbf, ROWS, QKVW, 512);
    vtrans_k<<<dim3(16, 64), 256, 0, stream>>>(QKVbf, VT);
    attn_k<<<dim3(8, 8, 8), 256, 0, stream>>>(QKVbf, VT, Zbf);
    gemm128_k<false, false, true, false><<<dim3(4, 64), 256, 0, stream>>>(
        Zbf, WtO + (size_t)l * 262144, nullptr, enc, E1, ROWS, 512, 512);
    // pre-LN FFN
    ln_k<<<2048, 256, 0, stream>>>(E1, gf + l * 512, bfn + l * 512, Ybf, ROWS);
    gemm128_k<true, true, false, true><<<dim3(16, 64), 256, 0, stream>>>(
        Ybf, Wt1 + (size_t)l * 1048576, b1 + l * 2048, nullptr, H1bf, ROWS, 2048, 512);
    gemm128_k<false, true, true, false><<<dim3(4, 64), 256, 0, stream>>>(
        H1bf, Wt2 + (size_t)l * 1048576, b2 + l * 512, E1, (l == 5) ? out : E0,
        ROWS, 512, 2048);
  }
}

// Round 3
// 1136.744 us; speedup vs baseline: 1.2899x; 1.1316x over previous
//
#include <hip/hip_runtime.h>

// 6-layer pre-LN encoder, B=8 S=1024 D=512 H=8 DH=64 FFN=2048.
// Round 3: attention occupancy 2->4 blocks/CU (64-row q tiles) + T13 defer-
// rescale; gemm64 variant for N=512 GEMMs (2 blocks/CU instead of 1).

#define SEQ 1024
#define ROWS 8192
#define QKVW 1536

using bf16x8 = __attribute__((ext_vector_type(8))) short;
using f32x4  = __attribute__((ext_vector_type(4))) float;

__device__ __forceinline__ unsigned short f2bf(float f) {
  union { float f; unsigned u; } v; v.f = f;
  unsigned r = v.u + 0x7FFFu + ((v.u >> 16) & 1u);   // RNE
  return (unsigned short)(r >> 16);
}

__device__ __forceinline__ void gl16(const void* g, void* l) {
  typedef const unsigned int __attribute__((address_space(1)))* GP;
  typedef unsigned int __attribute__((address_space(3)))* LP;
  __builtin_amdgcn_global_load_lds((GP)g, (LP)l, 16, 0, 0);
}

// ---------------------------------------------------------------- weight prep
__global__ __launch_bounds__(256) void transpose_cast_k(
    const float* __restrict__ W, unsigned short* __restrict__ Wt,
    int K, int N, int lstride, float scale)
{
  __shared__ float tile[32][33];
  const int l = blockIdx.z;
  const float* Wl = W + (size_t)l * K * N;
  unsigned short* Wtl = Wt + (size_t)l * lstride;
  const int k0 = blockIdx.y * 32, n0 = blockIdx.x * 32;
  const int tx = threadIdx.x & 31, ty = threadIdx.x >> 5;
  #pragma unroll
  for (int i = ty; i < 32; i += 8)
    tile[i][tx] = Wl[(size_t)(k0 + i) * N + n0 + tx];
  __syncthreads();
  #pragma unroll
  for (int i = ty; i < 32; i += 8)
    Wtl[(size_t)(n0 + i) * K + k0 + tx] = f2bf(tile[tx][i] * scale);
}

// ---------------------------------------------------------------- layernorm
__global__ __launch_bounds__(256) void ln_k(
    const float* __restrict__ x, const float* __restrict__ g,
    const float* __restrict__ be, unsigned short* __restrict__ y, int rows)
{
  const int wid = (blockIdx.x << 2) | (threadIdx.x >> 6);
  const int lane = threadIdx.x & 63;
  if (wid >= rows) return;
  const float4* xr = reinterpret_cast<const float4*>(x + (size_t)wid * 512);
  float4 a = xr[lane];
  float4 b = xr[lane + 64];
  float s = a.x + a.y + a.z + a.w + b.x + b.y + b.z + b.w;
  #pragma unroll
  for (int m = 32; m >= 1; m >>= 1) s += __shfl_xor(s, m);
  const float mu = s * (1.0f / 512.0f);
  const float d0 = a.x - mu, d1 = a.y - mu, d2 = a.z - mu, d3 = a.w - mu;
  const float e0 = b.x - mu, e1 = b.y - mu, e2 = b.z - mu, e3 = b.w - mu;
  float q = d0*d0 + d1*d1 + d2*d2 + d3*d3 + e0*e0 + e1*e1 + e2*e2 + e3*e3;
  #pragma unroll
  for (int m = 32; m >= 1; m >>= 1) q += __shfl_xor(q, m);
  const float inv = rsqrtf(q * (1.0f / 512.0f) + 1e-3f);
  const float4* gr = reinterpret_cast<const float4*>(g);
  const float4* br = reinterpret_cast<const float4*>(be);
  const float4 g0 = gr[lane], g1 = gr[lane + 64];
  const float4 h0 = br[lane], h1 = br[lane + 64];
  ushort4 o0, o1;
  o0.x = f2bf(d0 * inv * g0.x + h0.x);
  o0.y = f2bf(d1 * inv * g0.y + h0.y);
  o0.z = f2bf(d2 * inv * g0.z + h0.z);
  o0.w = f2bf(d3 * inv * g0.w + h0.w);
  o1.x = f2bf(e0 * inv * g1.x + h1.x);
  o1.y = f2bf(e1 * inv * g1.y + h1.y);
  o1.z = f2bf(e2 * inv * g1.z + h1.z);
  o1.w = f2bf(e3 * inv * g1.w + h1.w);
  *reinterpret_cast<ushort4*>(y + (size_t)wid * 512 + lane * 4) = o0;
  *reinterpret_cast<ushort4*>(y + (size_t)wid * 512 + (lane + 64) * 4) = o1;
}

// ---------------------------------------------------------------- GEMM 128x128
template<bool RELU, bool HASBIAS, bool HASRES, bool OUTBF>
__global__ __launch_bounds__(256) void gemm128_k(
    const unsigned short* __restrict__ A,
    const unsigned short* __restrict__ Wt,
    const float* __restrict__ bias,
    const float* __restrict__ res,
    void* __restrict__ outp, int M, int N, int K)
{
  __shared__ __align__(16) unsigned short As[4096];   // [128][32] linear
  __shared__ __align__(16) unsigned short Bs[4096];
  const int t = threadIdx.x;
  const int m0 = blockIdx.y * 128, n0 = blockIdx.x * 128;
  const int w = t >> 6, lane = t & 63, llo = lane & 15, lhi = lane >> 4;
  const int wr = w >> 1, wc = w & 1;

  const int sr = t >> 2, sc = (t & 3) * 8;
  const unsigned short* pa0 = &A[(size_t)(m0 + sr) * K + sc];
  const unsigned short* pa1 = &A[(size_t)(m0 + 64 + sr) * K + sc];
  const unsigned short* pb0 = &Wt[(size_t)(n0 + sr) * K + sc];
  const unsigned short* pb1 = &Wt[(size_t)(n0 + 64 + sr) * K + sc];
  unsigned short* la0 = &As[t * 8];
  unsigned short* la1 = &As[2048 + t * 8];
  unsigned short* lb0 = &Bs[t * 8];
  unsigned short* lb1 = &Bs[2048 + t * 8];

  f32x4 acc[4][4] = {};
  for (int k0 = 0; k0 < K; k0 += 32) {
    __syncthreads();
    gl16(pa0, la0); gl16(pa1, la1);
    gl16(pb0, lb0); gl16(pb1, lb1);
    pa0 += 32; pa1 += 32; pb0 += 32; pb1 += 32;
    __syncthreads();
    bf16x8 af[4], bfr[4];
    #pragma unroll
    for (int f = 0; f < 4; f++) {
      af[f]  = *reinterpret_cast<const bf16x8*>(&As[(wr * 64 + f * 16 + llo) * 32 + lhi * 8]);
      bfr[f] = *reinterpret_cast<const bf16x8*>(&Bs[(wc * 64 + f * 16 + llo) * 32 + lhi * 8]);
    }
    #pragma unroll
    for (int fi = 0; fi < 4; fi++)
      #pragma unroll
      for (int fj = 0; fj < 4; fj++)
        acc[fi][fj] = __builtin_amdgcn_mfma_f32_16x16x32_bf16(af[fi], bfr[fj], acc[fi][fj], 0, 0, 0);
  }

  const int row0 = m0 + wr * 64, col0 = n0 + wc * 64;
  #pragma unroll
  for (int fi = 0; fi < 4; fi++)
    #pragma unroll
    for (int fj = 0; fj < 4; fj++)
      #pragma unroll
      for (int i = 0; i < 4; i++) {
        const int row = row0 + fi * 16 + lhi * 4 + i;
        const int col = col0 + fj * 16 + llo;
        float v = acc[fi][fj][i];
        if (HASBIAS) v += bias[col];
        if (HASRES)  v += res[(size_t)row * N + col];
        if (RELU)    v = fmaxf(v, 0.0f);
        if (OUTBF) ((unsigned short*)outp)[(size_t)row * N + col] = f2bf(v);
        else       ((float*)outp)[(size_t)row * N + col] = v;
      }
}

// ---------------------------------------------------------------- GEMM 64x128
// For N=512 outputs: grid (4, M/64) = 512 blocks -> 2 blocks/CU.
template<bool RELU, bool HASBIAS, bool HASRES, bool OUTBF>
__global__ __launch_bounds__(256) void gemm64_k(
    const unsigned short* __restrict__ A,
    const unsigned short* __restrict__ Wt,
    const float* __restrict__ bias,
    const float* __restrict__ res,
    void* __restrict__ outp, int M, int N, int K)
{
  __shared__ __align__(16) unsigned short As[2048];   // [64][32] linear
  __shared__ __align__(16) unsigned short Bs[4096];   // [128][32] linear
  const int t = threadIdx.x;
  const int m0 = blockIdx.y * 64, n0 = blockIdx.x * 128;
  const int w = t >> 6, lane = t & 63, llo = lane & 15, lhi = lane >> 4;
  const int wr = w >> 1, wc = w & 1;

  const int sr = t >> 2, sc = (t & 3) * 8;
  const unsigned short* pa0 = &A[(size_t)(m0 + sr) * K + sc];
  const unsigned short* pb0 = &Wt[(size_t)(n0 + sr) * K + sc];
  const unsigned short* pb1 = &Wt[(size_t)(n0 + 64 + sr) * K + sc];
  unsigned short* la0 = &As[t * 8];
  unsigned short* lb0 = &Bs[t * 8];
  unsigned short* lb1 = &Bs[2048 + t * 8];

  f32x4 acc[2][4] = {};
  for (int k0 = 0; k0 < K; k0 += 32) {
    __syncthreads();
    gl16(pa0, la0);
    gl16(pb0, lb0); gl16(pb1, lb1);
    pa0 += 32; pb0 += 32; pb1 += 32;
    __syncthreads();
    bf16x8 af[2], bfr[4];
    #pragma unroll
    for (int f = 0; f < 2; f++)
      af[f] = *reinterpret_cast<const bf16x8*>(&As[(wr * 32 + f * 16 + llo) * 32 + lhi * 8]);
    #pragma unroll
    for (int f = 0; f < 4; f++)
      bfr[f] = *reinterpret_cast<const bf16x8*>(&Bs[(wc * 64 + f * 16 + llo) * 32 + lhi * 8]);
    #pragma unroll
    for (int fi = 0; fi < 2; fi++)
      #pragma unroll
      for (int fj = 0; fj < 4; fj++)
        acc[fi][fj] = __builtin_amdgcn_mfma_f32_16x16x32_bf16(af[fi], bfr[fj], acc[fi][fj], 0, 0, 0);
  }

  const int row0 = m0 + wr * 32, col0 = n0 + wc * 64;
  #pragma unroll
  for (int fi = 0; fi < 2; fi++)
    #pragma unroll
    for (int fj = 0; fj < 4; fj++)
      #pragma unroll
      for (int i = 0; i < 4; i++) {
        const int row = row0 + fi * 16 + lhi * 4 + i;
        const int col = col0 + fj * 16 + llo;
        float v = acc[fi][fj][i];
        if (HASBIAS) v += bias[col];
        if (HASRES)  v += res[(size_t)row * N + col];
        if (RELU)    v = fmaxf(v, 0.0f);
        if (OUTBF) ((unsigned short*)outp)[(size_t)row * N + col] = f2bf(v);
        else       ((float*)outp)[(size_t)row * N + col] = v;
      }
}

// ---------------------------------------------------------------- V transpose
__global__ __launch_bounds__(256) void vtrans_k(
    const unsigned short* __restrict__ QKV, unsigned short* __restrict__ VT)
{
  __shared__ unsigned short tile[64][66];
  const int kt = blockIdx.x, bh = blockIdx.y;
  const int bb = bh >> 3, h = bh & 7;
  const int t = threadIdx.x;
  const int r = t >> 2, c0 = (t & 3) * 16;
  const unsigned short* src = &QKV[((size_t)bb * SEQ + kt * 64 + r) * QKVW + 1024 + h * 64 + c0];
  *reinterpret_cast<uint4*>(&tile[r][c0])     = *reinterpret_cast<const uint4*>(src);
  *reinterpret_cast<uint4*>(&tile[r][c0 + 8]) = *reinterpret_cast<const uint4*>(src + 8);
  __syncthreads();
  const int dv = t >> 2, kv0 = (t & 3) * 16;
  unsigned short tmp[16];
  #pragma unroll
  for (int j = 0; j < 16; j++) tmp[j] = tile[kv0 + j][dv];
  ushort4 o0, o1, o2, o3;
  o0.x = tmp[0];  o0.y = tmp[1];  o0.z = tmp[2];  o0.w = tmp[3];
  o1.x = tmp[4];  o1.y = tmp[5];  o1.z = tmp[6];  o1.w = tmp[7];
  o2.x = tmp[8];  o2.y = tmp[9];  o2.z = tmp[10]; o2.w = tmp[11];
  o3.x = tmp[12]; o3.y = tmp[13]; o3.z = tmp[14]; o3.w = tmp[15];
  unsigned short* dst = &VT[((size_t)bh * 64 + dv) * SEQ + kt * 64 + kv0];
  *reinterpret_cast<ushort4*>(dst)      = o0;
  *reinterpret_cast<ushort4*>(dst + 4)  = o1;
  *reinterpret_cast<ushort4*>(dst + 8)  = o2;
  *reinterpret_cast<ushort4*>(dst + 12) = o3;
}

// ---------------------------------------------------------------- attention
// block = (qt 0..15, h, b); 4 waves x 16 q-rows; kv tiles of 64. 1024 blocks.
__global__ __launch_bounds__(256) void attn_k(
    const unsigned short* __restrict__ QKV,   // [8192][1536]; Q pre-scaled
    const unsigned short* __restrict__ VT,    // [bh][64][1024]
    unsigned short* __restrict__ Zb)          // [8192][512]
{
  __shared__ __align__(16) unsigned short Ks[4096];
  __shared__ __align__(16) unsigned short Vs[4096];
  __shared__ __align__(16) unsigned short Ps[4096];   // 4 waves x 1024

  const int t = threadIdx.x;
  const int qt = blockIdx.x, h = blockIdx.y, bb = blockIdx.z;
  const int w = t >> 6, lane = t & 63, llo = lane & 15, lhi = lane >> 4;
  const size_t rowb = (size_t)bb * SEQ;
  const int kcol = 512 + h * 64;
  const size_t vtb = (size_t)(bb * 8 + h) * 64 * SEQ;

  // hoist Q fragments (softmax scale folded into Wq)
  bf16x8 aq[2];
  #pragma unroll
  for (int ds = 0; ds < 2; ds++)
    aq[ds] = *reinterpret_cast<const bf16x8*>(
        &QKV[(rowb + qt * 64 + w * 16 + llo) * QKVW + h * 64 + ds * 32 + lhi * 8]);

  // frag-major staging sources (chunk c = iss*256 + t)
  const int cA = t, cB = 256 + t;
  const int gA = cA >> 6, lA = cA & 63, gB = cB >> 6, lB = cB & 63;
  const unsigned short* kpA = &QKV[(rowb + (gA >> 1) * 16 + (lA & 15)) * QKVW + kcol + (gA & 1) * 32 + (lA >> 4) * 8];
  const unsigned short* kpB = &QKV[(rowb + (gB >> 1) * 16 + (lB & 15)) * QKVW + kcol + (gB & 1) * 32 + (lB >> 4) * 8];
  const unsigned short* vpA = &VT[vtb + (size_t)((gA >> 1) * 16 + (lA & 15)) * SEQ + (gA & 1) * 32 + (lA >> 4) * 8];
  const unsigned short* vpB = &VT[vtb + (size_t)((gB >> 1) * 16 + (lB & 15)) * SEQ + (gB & 1) * 32 + (lB >> 4) * 8];
  unsigned short* lkA = &Ks[cA * 8];
  unsigned short* lkB = &Ks[cB * 8];
  unsigned short* lvA = &Vs[cA * 8];
  unsigned short* lvB = &Vs[cB * 8];

  float m_[4], l_[4];
  f32x4 o_[4] = {};
  #pragma unroll
  for (int i = 0; i < 4; i++) { m_[i] = -1e30f; l_[i] = 0.0f; }

  for (int kt = 0; kt < 16; kt++) {
    __syncthreads();
    gl16(kpA + (size_t)kt * 64 * QKVW, lkA);
    gl16(kpB + (size_t)kt * 64 * QKVW, lkB);
    gl16(vpA + kt * 64, lvA);
    gl16(vpB + kt * 64, lvB);
    __syncthreads();

    // QK^T: S[q 16][kv 64]
    f32x4 s_[4] = {};
    #pragma unroll
    for (int ds = 0; ds < 2; ds++)
      #pragma unroll
      for (int fj = 0; fj < 4; fj++) {
        bf16x8 bk = *reinterpret_cast<const bf16x8*>(&Ks[((fj * 2 + ds) * 64 + lane) * 8]);
        s_[fj] = __builtin_amdgcn_mfma_f32_16x16x32_bf16(aq[ds], bk, s_[fj], 0, 0, 0);
      }

    // tile row maxes (rows lhi*4+i, cols fj*16+llo)
    float tm[4];
    #pragma unroll
    for (int i = 0; i < 4; i++) {
      float v = fmaxf(fmaxf(s_[0][i], s_[1][i]), fmaxf(s_[2][i], s_[3][i]));
      v = fmaxf(v, __shfl_xor(v, 1));
      v = fmaxf(v, __shfl_xor(v, 2));
      v = fmaxf(v, __shfl_xor(v, 4));
      v = fmaxf(v, __shfl_xor(v, 8));
      tm[i] = v;
    }
    // T13 defer-rescale: skip when max growth <= 8 for every row in the wave
    float need = fmaxf(fmaxf(tm[0] - m_[0], tm[1] - m_[1]),
                       fmaxf(tm[2] - m_[2], tm[3] - m_[3]));
    if (!__all(need <= 8.0f)) {
      #pragma unroll
      for (int i = 0; i < 4; i++) {
        const float mn = fmaxf(m_[i], tm[i]);
        const float al = __expf(m_[i] - mn);
        l_[i] *= al;
        m_[i] = mn;
        #pragma unroll
        for (int fo = 0; fo < 4; fo++) o_[fo][i] *= al;
      }
    }
    #pragma unroll
    for (int i = 0; i < 4; i++) {
      float ps = 0.0f;
      #pragma unroll
      for (int fj = 0; fj < 4; fj++) {
        const float p = __expf(s_[fj][i] - m_[i]);
        ps += p;
        Ps[w * 1024 + (fj >> 1) * 512 + ((fj & 1) * 2 + (llo >> 3)) * 128
           + (lhi * 4 + i) * 8 + (llo & 7)] = f2bf(p);
      }
      ps += __shfl_xor(ps, 1);
      ps += __shfl_xor(ps, 2);
      ps += __shfl_xor(ps, 4);
      ps += __shfl_xor(ps, 8);
      l_[i] += ps;
    }

    // PV: O[q 16][dv 64] += P @ V
    #pragma unroll
    for (int ks = 0; ks < 2; ks++) {
      bf16x8 ap = *reinterpret_cast<const bf16x8*>(&Ps[w * 1024 + (ks * 64 + lane) * 8]);
      #pragma unroll
      for (int fo = 0; fo < 4; fo++) {
        bf16x8 bv = *reinterpret_cast<const bf16x8*>(&Vs[((fo * 2 + ks) * 64 + lane) * 8]);
        o_[fo] = __builtin_amdgcn_mfma_f32_16x16x32_bf16(ap, bv, o_[fo], 0, 0, 0);
      }
    }
  }

  #pragma unroll
  for (int fo = 0; fo < 4; fo++)
    #pragma unroll
    for (int i = 0; i < 4; i++) {
      const float v = o_[fo][i] / l_[i];
      Zb[(rowb + qt * 64 + w * 16 + lhi * 4 + i) * 512 + h * 64 + fo * 16 + llo] = f2bf(v);
    }
}

// ---------------------------------------------------------------- driver
extern "C" void kernel_launch(void* const* d_in, const int* in_sizes, int n_in,
                              void* d_out, int out_size, void* d_ws, size_t ws_size,
                              hipStream_t stream)
{
  const float* x   = (const float*)d_in[0];
  const float* Wq  = (const float*)d_in[1];
  const float* Wk  = (const float*)d_in[2];
  const float* Wv  = (const float*)d_in[3];
  const float* Wo  = (const float*)d_in[4];
  const float* W1  = (const float*)d_in[5];
  const float* b1  = (const float*)d_in[6];
  const float* W2  = (const float*)d_in[7];
  const float* b2  = (const float*)d_in[8];
  const float* ga  = (const float*)d_in[9];
  const float* ba  = (const float*)d_in[10];
  const float* gf  = (const float*)d_in[11];
  const float* bfn = (const float*)d_in[12];
  float* out = (float*)d_out;

  char* p = (char*)d_ws;
  auto alloc = [&](size_t bytes) { void* r = (void*)p; p += (bytes + 255) & ~(size_t)255; return r; };
  float* E0 = (float*)alloc((size_t)ROWS * 512 * 4);
  float* E1 = (float*)alloc((size_t)ROWS * 512 * 4);
  unsigned short* Ybf   = (unsigned short*)alloc((size_t)ROWS * 512 * 2);
  unsigned short* QKVbf = (unsigned short*)alloc((size_t)ROWS * QKVW * 2);
  unsigned short* H1bf  = (unsigned short*)alloc((size_t)ROWS * 2048 * 2);
  unsigned short* VT    = H1bf;   // aliases front 8MB of H1bf (disjoint in time)
  unsigned short* WtQKV = (unsigned short*)alloc(6ull * QKVW * 512 * 2);
  unsigned short* WtO   = (unsigned short*)alloc(6ull * 512 * 512 * 2);
  unsigned short* Wt1   = (unsigned short*)alloc(6ull * 2048 * 512 * 2);
  unsigned short* Wt2   = (unsigned short*)alloc(6ull * 512 * 2048 * 2);
  unsigned short* Zbf   = Ybf;

  // weight prep (Wq scaled by softmax 1/sqrt(DH)=0.125)
  transpose_cast_k<<<dim3(16, 16, 6), 256, 0, stream>>>(Wq, WtQKV,          512, 512,  QKVW * 512, 0.125f);
  transpose_cast_k<<<dim3(16, 16, 6), 256, 0, stream>>>(Wk, WtQKV + 262144, 512, 512,  QKVW * 512, 1.0f);
  transpose_cast_k<<<dim3(16, 16, 6), 256, 0, stream>>>(Wv, WtQKV + 524288, 512, 512,  QKVW * 512, 1.0f);
  transpose_cast_k<<<dim3(16, 16, 6), 256, 0, stream>>>(Wo, WtO,            512, 512,  262144,     1.0f);
  transpose_cast_k<<<dim3(64, 16, 6), 256, 0, stream>>>(W1, Wt1,            512, 2048, 1048576,    1.0f);
  transpose_cast_k<<<dim3(16, 64, 6), 256, 0, stream>>>(W2, Wt2,            2048, 512, 1048576,    1.0f);

  for (int l = 0; l < 6; l++) {
    const float* enc = (l == 0) ? x : E0;
    // pre-LN attention
    ln_k<<<2048, 256, 0, stream>>>(enc, ga + l * 512, ba + l * 512, Ybf, ROWS);
    gemm128_k<false, false, false, true><<<dim3(12, 64), 256, 0, stream>>>(
        Ybf, WtQKV + (size_t)l * QKVW * 512, nullptr, nullptr, QKVbf, ROWS, QKVW, 512);
    vtrans_k<<<dim3(16, 64), 256, 0, stream>>>(QKVbf, VT);
    attn_k<<<dim3(16, 8, 8), 256, 0, stream>>>(QKVbf, VT, Zbf);
    gemm64_k<false, false, true, false><<<dim3(4, 128), 256, 0, stream>>>(
        Zbf, WtO + (size_t)l * 262144, nullptr, enc, E1, ROWS, 512, 512);
    // pre-LN FFN
    ln_k<<<2048, 256, 0, stream>>>(E1, gf + l * 512, bfn + l * 512, Ybf, ROWS);
    gemm128_k<true, true, false, true><<<dim3(16, 64), 256, 0, stream>>>(
        Ybf, Wt1 + (size_t)l * 1048576, b1 + l * 2048, nullptr, H1bf, ROWS, 2048, 512);
    gemm64_k<false, true, true, false><<<dim3(4, 128), 256, 0, stream>>>(
        H1bf, Wt2 + (size_t)l * 1048576, b2 + l * 512, E1, (l == 5) ? out : E0,
        ROWS, 512, 2048);
  }
}

// Round 4
// 986.020 us; speedup vs baseline: 1.4870x; 1.1529x over previous
//
#include <hip/hip_runtime.h>

// 6-layer pre-LN encoder, B=8 S=1024 D=512 H=8 DH=64 FFN=2048.
// Round 4: (a) attention static-max log2-domain softmax (no per-tile
// reductions, v_exp_f32 direct, acc init -M0); (b) GEMM BK=64 with
// granule-XOR LDS swizzle (T2 both-sides: pre-swizzled global source +
// swizzled ds_read), halving barrier count per K.

#define SEQ 1024
#define ROWS 8192
#define QKVW 1536

using bf16x8 = __attribute__((ext_vector_type(8))) short;
using f32x4  = __attribute__((ext_vector_type(4))) float;

__device__ __forceinline__ unsigned short f2bf(float f) {
  union { float f; unsigned u; } v; v.f = f;
  unsigned r = v.u + 0x7FFFu + ((v.u >> 16) & 1u);   // RNE
  return (unsigned short)(r >> 16);
}

__device__ __forceinline__ float exp2_fast(float x) {
  float r;
  asm("v_exp_f32 %0, %1" : "=v"(r) : "v"(x));
  return r;
}

__device__ __forceinline__ void gl16(const void* g, void* l) {
  typedef const unsigned int __attribute__((address_space(1)))* GP;
  typedef unsigned int __attribute__((address_space(3)))* LP;
  __builtin_amdgcn_global_load_lds((GP)g, (LP)l, 16, 0, 0);
}

// ---------------------------------------------------------------- weight prep
__global__ __launch_bounds__(256) void transpose_cast_k(
    const float* __restrict__ W, unsigned short* __restrict__ Wt,
    int K, int N, int lstride, float scale)
{
  __shared__ float tile[32][33];
  const int l = blockIdx.z;
  const float* Wl = W + (size_t)l * K * N;
  unsigned short* Wtl = Wt + (size_t)l * lstride;
  const int k0 = blockIdx.y * 32, n0 = blockIdx.x * 32;
  const int tx = threadIdx.x & 31, ty = threadIdx.x >> 5;
  #pragma unroll
  for (int i = ty; i < 32; i += 8)
    tile[i][tx] = Wl[(size_t)(k0 + i) * N + n0 + tx];
  __syncthreads();
  #pragma unroll
  for (int i = ty; i < 32; i += 8)
    Wtl[(size_t)(n0 + i) * K + k0 + tx] = f2bf(tile[tx][i] * scale);
}

// ---------------------------------------------------------------- layernorm
__global__ __launch_bounds__(256) void ln_k(
    const float* __restrict__ x, const float* __restrict__ g,
    const float* __restrict__ be, unsigned short* __restrict__ y, int rows)
{
  const int wid = (blockIdx.x << 2) | (threadIdx.x >> 6);
  const int lane = threadIdx.x & 63;
  if (wid >= rows) return;
  const float4* xr = reinterpret_cast<const float4*>(x + (size_t)wid * 512);
  float4 a = xr[lane];
  float4 b = xr[lane + 64];
  float s = a.x + a.y + a.z + a.w + b.x + b.y + b.z + b.w;
  #pragma unroll
  for (int m = 32; m >= 1; m >>= 1) s += __shfl_xor(s, m);
  const float mu = s * (1.0f / 512.0f);
  const float d0 = a.x - mu, d1 = a.y - mu, d2 = a.z - mu, d3 = a.w - mu;
  const float e0 = b.x - mu, e1 = b.y - mu, e2 = b.z - mu, e3 = b.w - mu;
  float q = d0*d0 + d1*d1 + d2*d2 + d3*d3 + e0*e0 + e1*e1 + e2*e2 + e3*e3;
  #pragma unroll
  for (int m = 32; m >= 1; m >>= 1) q += __shfl_xor(q, m);
  const float inv = rsqrtf(q * (1.0f / 512.0f) + 1e-3f);
  const float4* gr = reinterpret_cast<const float4*>(g);
  const float4* br = reinterpret_cast<const float4*>(be);
  const float4 g0 = gr[lane], g1 = gr[lane + 64];
  const float4 h0 = br[lane], h1 = br[lane + 64];
  ushort4 o0, o1;
  o0.x = f2bf(d0 * inv * g0.x + h0.x);
  o0.y = f2bf(d1 * inv * g0.y + h0.y);
  o0.z = f2bf(d2 * inv * g0.z + h0.z);
  o0.w = f2bf(d3 * inv * g0.w + h0.w);
  o1.x = f2bf(e0 * inv * g1.x + h1.x);
  o1.y = f2bf(e1 * inv * g1.y + h1.y);
  o1.z = f2bf(e2 * inv * g1.z + h1.z);
  o1.w = f2bf(e3 * inv * g1.w + h1.w);
  *reinterpret_cast<ushort4*>(y + (size_t)wid * 512 + lane * 4) = o0;
  *reinterpret_cast<ushort4*>(y + (size_t)wid * 512 + (lane + 64) * 4) = o1;
}

// ---------------------------------------------------------------- GEMM 128x128, BK=64, XOR-swizzled LDS
// LDS physical granule (r,g) holds logical (r, g^(r&7)); source pre-swizzled.
template<bool RELU, bool HASBIAS, bool HASRES, bool OUTBF>
__global__ __launch_bounds__(256) void gemm128_k(
    const unsigned short* __restrict__ A,
    const unsigned short* __restrict__ Wt,
    const float* __restrict__ bias,
    const float* __restrict__ res,
    void* __restrict__ outp, int M, int N, int K)
{
  __shared__ __align__(16) unsigned short As[8192];   // [128][64] physical
  __shared__ __align__(16) unsigned short Bs[8192];
  const int t = threadIdx.x;
  const int m0 = blockIdx.y * 128, n0 = blockIdx.x * 128;
  const int w = t >> 6, lane = t & 63, llo = lane & 15, lhi = lane >> 4;
  const int wr = w >> 1, wc = w & 1;

  // staging: chunk c = i*256+t -> row i*32+(t>>3), phys granule t&7,
  // source granule sg = (t&7) ^ ((t>>3)&7)  (i*32 is 0 mod 8)
  const int sr = t >> 3, sg = (t & 7) ^ (sr & 7);
  const unsigned short* pa = &A[(size_t)(m0 + sr) * K + sg * 8];
  const unsigned short* pb = &Wt[(size_t)(n0 + sr) * K + sg * 8];
  unsigned short* la = &As[t * 8];
  unsigned short* lb = &Bs[t * 8];

  f32x4 acc[4][4] = {};
  for (int k0 = 0; k0 < K; k0 += 64) {
    __syncthreads();
    #pragma unroll
    for (int i = 0; i < 4; i++) {
      gl16(pa + (size_t)i * 32 * K, la + i * 2048);
      gl16(pb + (size_t)i * 32 * K, lb + i * 2048);
    }
    pa += 64; pb += 64;
    __syncthreads();
    #pragma unroll
    for (int kk = 0; kk < 2; kk++) {
      const int pg8 = (((kk << 2) | lhi) ^ (llo & 7)) * 8;
      bf16x8 af[4], bfr[4];
      #pragma unroll
      for (int f = 0; f < 4; f++) {
        af[f]  = *reinterpret_cast<const bf16x8*>(&As[(wr * 64 + f * 16 + llo) * 64 + pg8]);
        bfr[f] = *reinterpret_cast<const bf16x8*>(&Bs[(wc * 64 + f * 16 + llo) * 64 + pg8]);
      }
      #pragma unroll
      for (int fi = 0; fi < 4; fi++)
        #pragma unroll
        for (int fj = 0; fj < 4; fj++)
          acc[fi][fj] = __builtin_amdgcn_mfma_f32_16x16x32_bf16(af[fi], bfr[fj], acc[fi][fj], 0, 0, 0);
    }
  }

  const int row0 = m0 + wr * 64, col0 = n0 + wc * 64;
  #pragma unroll
  for (int fi = 0; fi < 4; fi++)
    #pragma unroll
    for (int fj = 0; fj < 4; fj++)
      #pragma unroll
      for (int i = 0; i < 4; i++) {
        const int row = row0 + fi * 16 + lhi * 4 + i;
        const int col = col0 + fj * 16 + llo;
        float v = acc[fi][fj][i];
        if (HASBIAS) v += bias[col];
        if (HASRES)  v += res[(size_t)row * N + col];
        if (RELU)    v = fmaxf(v, 0.0f);
        if (OUTBF) ((unsigned short*)outp)[(size_t)row * N + col] = f2bf(v);
        else       ((float*)outp)[(size_t)row * N + col] = v;
      }
}

// ---------------------------------------------------------------- GEMM 64x128, BK=64, swizzled
template<bool RELU, bool HASBIAS, bool HASRES, bool OUTBF>
__global__ __launch_bounds__(256) void gemm64_k(
    const unsigned short* __restrict__ A,
    const unsigned short* __restrict__ Wt,
    const float* __restrict__ bias,
    const float* __restrict__ res,
    void* __restrict__ outp, int M, int N, int K)
{
  __shared__ __align__(16) unsigned short As[4096];   // [64][64] physical
  __shared__ __align__(16) unsigned short Bs[8192];   // [128][64] physical
  const int t = threadIdx.x;
  const int m0 = blockIdx.y * 64, n0 = blockIdx.x * 128;
  const int w = t >> 6, lane = t & 63, llo = lane & 15, lhi = lane >> 4;
  const int wr = w >> 1, wc = w & 1;

  const int sr = t >> 3, sg = (t & 7) ^ (sr & 7);
  const unsigned short* pa = &A[(size_t)(m0 + sr) * K + sg * 8];
  const unsigned short* pb = &Wt[(size_t)(n0 + sr) * K + sg * 8];
  unsigned short* la = &As[t * 8];
  unsigned short* lb = &Bs[t * 8];

  f32x4 acc[2][4] = {};
  for (int k0 = 0; k0 < K; k0 += 64) {
    __syncthreads();
    #pragma unroll
    for (int i = 0; i < 2; i++)
      gl16(pa + (size_t)i * 32 * K, la + i * 2048);
    #pragma unroll
    for (int i = 0; i < 4; i++)
      gl16(pb + (size_t)i * 32 * K, lb + i * 2048);
    pa += 64; pb += 64;
    __syncthreads();
    #pragma unroll
    for (int kk = 0; kk < 2; kk++) {
      const int pg8 = (((kk << 2) | lhi) ^ (llo & 7)) * 8;
      bf16x8 af[2], bfr[4];
      #pragma unroll
      for (int f = 0; f < 2; f++)
        af[f] = *reinterpret_cast<const bf16x8*>(&As[(wr * 32 + f * 16 + llo) * 64 + pg8]);
      #pragma unroll
      for (int f = 0; f < 4; f++)
        bfr[f] = *reinterpret_cast<const bf16x8*>(&Bs[(wc * 64 + f * 16 + llo) * 64 + pg8]);
      #pragma unroll
      for (int fi = 0; fi < 2; fi++)
        #pragma unroll
        for (int fj = 0; fj < 4; fj++)
          acc[fi][fj] = __builtin_amdgcn_mfma_f32_16x16x32_bf16(af[fi], bfr[fj], acc[fi][fj], 0, 0, 0);
    }
  }

  const int row0 = m0 + wr * 32, col0 = n0 + wc * 64;
  #pragma unroll
  for (int fi = 0; fi < 2; fi++)
    #pragma unroll
    for (int fj = 0; fj < 4; fj++)
      #pragma unroll
      for (int i = 0; i < 4; i++) {
        const int row = row0 + fi * 16 + lhi * 4 + i;
        const int col = col0 + fj * 16 + llo;
        float v = acc[fi][fj][i];
        if (HASBIAS) v += bias[col];
        if (HASRES)  v += res[(size_t)row * N + col];
        if (RELU)    v = fmaxf(v, 0.0f);
        if (OUTBF) ((unsigned short*)outp)[(size_t)row * N + col] = f2bf(v);
        else       ((float*)outp)[(size_t)row * N + col] = v;
      }
}

// ---------------------------------------------------------------- V transpose
__global__ __launch_bounds__(256) void vtrans_k(
    const unsigned short* __restrict__ QKV, unsigned short* __restrict__ VT)
{
  __shared__ unsigned short tile[64][66];
  const int kt = blockIdx.x, bh = blockIdx.y;
  const int bb = bh >> 3, h = bh & 7;
  const int t = threadIdx.x;
  const int r = t >> 2, c0 = (t & 3) * 16;
  const unsigned short* src = &QKV[((size_t)bb * SEQ + kt * 64 + r) * QKVW + 1024 + h * 64 + c0];
  *reinterpret_cast<uint4*>(&tile[r][c0])     = *reinterpret_cast<const uint4*>(src);
  *reinterpret_cast<uint4*>(&tile[r][c0 + 8]) = *reinterpret_cast<const uint4*>(src + 8);
  __syncthreads();
  const int dv = t >> 2, kv0 = (t & 3) * 16;
  unsigned short tmp[16];
  #pragma unroll
  for (int j = 0; j < 16; j++) tmp[j] = tile[kv0 + j][dv];
  ushort4 o0, o1, o2, o3;
  o0.x = tmp[0];  o0.y = tmp[1];  o0.z = tmp[2];  o0.w = tmp[3];
  o1.x = tmp[4];  o1.y = tmp[5];  o1.z = tmp[6];  o1.w = tmp[7];
  o2.x = tmp[8];  o2.y = tmp[9];  o2.z = tmp[10]; o2.w = tmp[11];
  o3.x = tmp[12]; o3.y = tmp[13]; o3.z = tmp[14]; o3.w = tmp[15];
  unsigned short* dst = &VT[((size_t)bh * 64 + dv) * SEQ + kt * 64 + kv0];
  *reinterpret_cast<ushort4*>(dst)      = o0;
  *reinterpret_cast<ushort4*>(dst + 4)  = o1;
  *reinterpret_cast<ushort4*>(dst + 8)  = o2;
  *reinterpret_cast<ushort4*>(dst + 12) = o3;
}

// ---------------------------------------------------------------- attention
// block = (qt 0..15, h, b); 4 waves x 16 q-rows; kv tiles of 64.
// Static-max softmax in log2 domain: Q pre-scaled by 0.125*log2e, QK acc
// init -16, P = exp2(s2-16) via v_exp_f32. l accumulated per-lane, reduced
// once after the loop (no per-tile shuffles, no max tracking).
__global__ __launch_bounds__(256) void attn_k(
    const unsigned short* __restrict__ QKV,   // [8192][1536]
    const unsigned short* __restrict__ VT,    // [bh][64][1024]
    unsigned short* __restrict__ Zb)          // [8192][512]
{
  __shared__ __align__(16) unsigned short Ks[4096];
  __shared__ __align__(16) unsigned short Vs[4096];
  __shared__ __align__(16) unsigned short Ps[4096];   // 4 waves x 1024

  const int t = threadIdx.x;
  const int qt = blockIdx.x, h = blockIdx.y, bb = blockIdx.z;
  const int w = t >> 6, lane = t & 63, llo = lane & 15, lhi = lane >> 4;
  const size_t rowb = (size_t)bb * SEQ;
  const int kcol = 512 + h * 64;
  const size_t vtb = (size_t)(bb * 8 + h) * 64 * SEQ;

  // hoist Q fragments (0.125*log2e folded into Wq)
  bf16x8 aq[2];
  #pragma unroll
  for (int ds = 0; ds < 2; ds++)
    aq[ds] = *reinterpret_cast<const bf16x8*>(
        &QKV[(rowb + qt * 64 + w * 16 + llo) * QKVW + h * 64 + ds * 32 + lhi * 8]);

  // frag-major staging sources (chunk c = iss*256 + t)
  const int cA = t, cB = 256 + t;
  const int gA = cA >> 6, lA = cA & 63, gB = cB >> 6, lB = cB & 63;
  const unsigned short* kpA = &QKV[(rowb + (gA >> 1) * 16 + (lA & 15)) * QKVW + kcol + (gA & 1) * 32 + (lA >> 4) * 8];
  const unsigned short* kpB = &QKV[(rowb + (gB >> 1) * 16 + (lB & 15)) * QKVW + kcol + (gB & 1) * 32 + (lB >> 4) * 8];
  const unsigned short* vpA = &VT[vtb + (size_t)((gA >> 1) * 16 + (lA & 15)) * SEQ + (gA & 1) * 32 + (lA >> 4) * 8];
  const unsigned short* vpB = &VT[vtb + (size_t)((gB >> 1) * 16 + (lB & 15)) * SEQ + (gB & 1) * 32 + (lB >> 4) * 8];
  unsigned short* lkA = &Ks[cA * 8];
  unsigned short* lkB = &Ks[cB * 8];
  unsigned short* lvA = &Vs[cA * 8];
  unsigned short* lvB = &Vs[cB * 8];

  float l_[4] = {0.0f, 0.0f, 0.0f, 0.0f};
  f32x4 o_[4] = {};

  for (int kt = 0; kt < 16; kt++) {
    __syncthreads();
    gl16(kpA + (size_t)kt * 64 * QKVW, lkA);
    gl16(kpB + (size_t)kt * 64 * QKVW, lkB);
    gl16(vpA + kt * 64, lvA);
    gl16(vpB + kt * 64, lvB);
    __syncthreads();

    // QK^T in log2 domain, acc pre-biased by -M0=-16
    f32x4 s_[4];
    #pragma unroll
    for (int fj = 0; fj < 4; fj++)
      #pragma unroll
      for (int i = 0; i < 4; i++) s_[fj][i] = -16.0f;
    #pragma unroll
    for (int ds = 0; ds < 2; ds++)
      #pragma unroll
      for (int fj = 0; fj < 4; fj++) {
        bf16x8 bk = *reinterpret_cast<const bf16x8*>(&Ks[((fj * 2 + ds) * 64 + lane) * 8]);
        s_[fj] = __builtin_amdgcn_mfma_f32_16x16x32_bf16(aq[ds], bk, s_[fj], 0, 0, 0);
      }

    // P = exp2(s2), accumulate l per-lane, write bf16 P frags
    #pragma unroll
    for (int fj = 0; fj < 4; fj++)
      #pragma unroll
      for (int i = 0; i < 4; i++) {
        const float p = exp2_fast(s_[fj][i]);
        l_[i] += p;
        Ps[w * 1024 + (fj >> 1) * 512 + ((fj & 1) * 2 + (llo >> 3)) * 128
           + (lhi * 4 + i) * 8 + (llo & 7)] = f2bf(p);
      }

    // PV: O[q 16][dv 64] += P @ V
    #pragma unroll
    for (int ks = 0; ks < 2; ks++) {
      bf16x8 ap = *reinterpret_cast<const bf16x8*>(&Ps[w * 1024 + (ks * 64 + lane) * 8]);
      #pragma unroll
      for (int fo = 0; fo < 4; fo++) {
        bf16x8 bv = *reinterpret_cast<const bf16x8*>(&Vs[((fo * 2 + ks) * 64 + lane) * 8]);
        o_[fo] = __builtin_amdgcn_mfma_f32_16x16x32_bf16(ap, bv, o_[fo], 0, 0, 0);
      }
    }
  }

  // single end-of-loop l reduction across the 16 column-lanes
  #pragma unroll
  for (int i = 0; i < 4; i++) {
    l_[i] += __shfl_xor(l_[i], 1);
    l_[i] += __shfl_xor(l_[i], 2);
    l_[i] += __shfl_xor(l_[i], 4);
    l_[i] += __shfl_xor(l_[i], 8);
  }

  #pragma unroll
  for (int fo = 0; fo < 4; fo++)
    #pragma unroll
    for (int i = 0; i < 4; i++) {
      const float v = o_[fo][i] / l_[i];
      Zb[(rowb + qt * 64 + w * 16 + lhi * 4 + i) * 512 + h * 64 + fo * 16 + llo] = f2bf(v);
    }
}

// ---------------------------------------------------------------- driver
extern "C" void kernel_launch(void* const* d_in, const int* in_sizes, int n_in,
                              void* d_out, int out_size, void* d_ws, size_t ws_size,
                              hipStream_t stream)
{
  const float* x   = (const float*)d_in[0];
  const float* Wq  = (const float*)d_in[1];
  const float* Wk  = (const float*)d_in[2];
  const float* Wv  = (const float*)d_in[3];
  const float* Wo  = (const float*)d_in[4];
  const float* W1  = (const float*)d_in[5];
  const float* b1  = (const float*)d_in[6];
  const float* W2  = (const float*)d_in[7];
  const float* b2  = (const float*)d_in[8];
  const float* ga  = (const float*)d_in[9];
  const float* ba  = (const float*)d_in[10];
  const float* gf  = (const float*)d_in[11];
  const float* bfn = (const float*)d_in[12];
  float* out = (float*)d_out;

  char* p = (char*)d_ws;
  auto alloc = [&](size_t bytes) { void* r = (void*)p; p += (bytes + 255) & ~(size_t)255; return r; };
  float* E0 = (float*)alloc((size_t)ROWS * 512 * 4);
  float* E1 = (float*)alloc((size_t)ROWS * 512 * 4);
  unsigned short* Ybf   = (unsigned short*)alloc((size_t)ROWS * 512 * 2);
  unsigned short* QKVbf = (unsigned short*)alloc((size_t)ROWS * QKVW * 2);
  unsigned short* H1bf  = (unsigned short*)alloc((size_t)ROWS * 2048 * 2);
  unsigned short* VT    = H1bf;   // aliases front 8MB of H1bf (disjoint in time)
  unsigned short* WtQKV = (unsigned short*)alloc(6ull * QKVW * 512 * 2);
  unsigned short* WtO   = (unsigned short*)alloc(6ull * 512 * 512 * 2);
  unsigned short* Wt1   = (unsigned short*)alloc(6ull * 2048 * 512 * 2);
  unsigned short* Wt2   = (unsigned short*)alloc(6ull * 512 * 2048 * 2);
  unsigned short* Zbf   = Ybf;

  // weight prep (Wq carries softmax scale AND log2e for exp2-domain softmax)
  const float qscale = 0.125f * 1.44269504f;
  transpose_cast_k<<<dim3(16, 16, 6), 256, 0, stream>>>(Wq, WtQKV,          512, 512,  QKVW * 512, qscale);
  transpose_cast_k<<<dim3(16, 16, 6), 256, 0, stream>>>(Wk, WtQKV + 262144, 512, 512,  QKVW * 512, 1.0f);
  transpose_cast_k<<<dim3(16, 16, 6), 256, 0, stream>>>(Wv, WtQKV + 524288, 512, 512,  QKVW * 512, 1.0f);
  transpose_cast_k<<<dim3(16, 16, 6), 256, 0, stream>>>(Wo, WtO,            512, 512,  262144,     1.0f);
  transpose_cast_k<<<dim3(64, 16, 6), 256, 0, stream>>>(W1, Wt1,            512, 2048, 1048576,    1.0f);
  transpose_cast_k<<<dim3(16, 64, 6), 256, 0, stream>>>(W2, Wt2,            2048, 512, 1048576,    1.0f);

  for (int l = 0; l < 6; l++) {
    const float* enc = (l == 0) ? x : E0;
    // pre-LN attention
    ln_k<<<2048, 256, 0, stream>>>(enc, ga + l * 512, ba + l * 512, Ybf, ROWS);
    gemm128_k<false, false, false, true><<<dim3(12, 64), 256, 0, stream>>>(
        Ybf, WtQKV + (size_t)l * QKVW * 512, nullptr, nullptr, QKVbf, ROWS, QKVW, 512);
    vtrans_k<<<dim3(16, 64), 256, 0, stream>>>(QKVbf, VT);
    attn_k<<<dim3(16, 8, 8), 256, 0, stream>>>(QKVbf, VT, Zbf);
    gemm64_k<false, false, true, false><<<dim3(4, 128), 256, 0, stream>>>(
        Zbf, WtO + (size_t)l * 262144, nullptr, enc, E1, ROWS, 512, 512);
    // pre-LN FFN
    ln_k<<<2048, 256, 0, stream>>>(E1, gf + l * 512, bfn + l * 512, Ybf, ROWS);
    gemm128_k<true, true, false, true><<<dim3(16, 64), 256, 0, stream>>>(
        Ybf, Wt1 + (size_t)l * 1048576, b1 + l * 2048, nullptr, H1bf, ROWS, 2048, 512);
    gemm64_k<false, true, true, false><<<dim3(4, 128), 256, 0, stream>>>(
        H1bf, Wt2 + (size_t)l * 1048576, b2 + l * 512, E1, (l == 5) ? out : E0,
        ROWS, 512, 2048);
  }
}

// Round 5
// 904.608 us; speedup vs baseline: 1.6209x; 1.0900x over previous
//
#include <hip/hip_runtime.h>

// 6-layer pre-LN encoder, B=8 S=1024 D=512 H=8 DH=64 FFN=2048.
// Round 5: 2-phase double-buffered pipelines (stage t+1 issued before
// compute t, ONE barrier per tile) in all GEMMs + attention; BK=32 with
// granule-XOR swizzle (both-sides); XCD-aware bijective block remap.

#define SEQ 1024
#define ROWS 8192
#define QKVW 1536

using bf16x8 = __attribute__((ext_vector_type(8))) short;
using f32x4  = __attribute__((ext_vector_type(4))) float;

__device__ __forceinline__ unsigned short f2bf(float f) {
  union { float f; unsigned u; } v; v.f = f;
  unsigned r = v.u + 0x7FFFu + ((v.u >> 16) & 1u);   // RNE
  return (unsigned short)(r >> 16);
}

__device__ __forceinline__ float exp2_fast(float x) {
  float r;
  asm("v_exp_f32 %0, %1" : "=v"(r) : "v"(x));
  return r;
}

__device__ __forceinline__ void gl16(const void* g, void* l) {
  typedef const unsigned int __attribute__((address_space(1)))* GP;
  typedef unsigned int __attribute__((address_space(3)))* LP;
  __builtin_amdgcn_global_load_lds((GP)g, (LP)l, 16, 0, 0);
}

// ---------------------------------------------------------------- weight prep
__global__ __launch_bounds__(256) void transpose_cast_k(
    const float* __restrict__ W, unsigned short* __restrict__ Wt,
    int K, int N, int lstride, float scale)
{
  __shared__ float tile[32][33];
  const int l = blockIdx.z;
  const float* Wl = W + (size_t)l * K * N;
  unsigned short* Wtl = Wt + (size_t)l * lstride;
  const int k0 = blockIdx.y * 32, n0 = blockIdx.x * 32;
  const int tx = threadIdx.x & 31, ty = threadIdx.x >> 5;
  #pragma unroll
  for (int i = ty; i < 32; i += 8)
    tile[i][tx] = Wl[(size_t)(k0 + i) * N + n0 + tx];
  __syncthreads();
  #pragma unroll
  for (int i = ty; i < 32; i += 8)
    Wtl[(size_t)(n0 + i) * K + k0 + tx] = f2bf(tile[tx][i] * scale);
}

// ---------------------------------------------------------------- layernorm
__global__ __launch_bounds__(256) void ln_k(
    const float* __restrict__ x, const float* __restrict__ g,
    const float* __restrict__ be, unsigned short* __restrict__ y, int rows)
{
  const int wid = (blockIdx.x << 2) | (threadIdx.x >> 6);
  const int lane = threadIdx.x & 63;
  if (wid >= rows) return;
  const float4* xr = reinterpret_cast<const float4*>(x + (size_t)wid * 512);
  float4 a = xr[lane];
  float4 b = xr[lane + 64];
  float s = a.x + a.y + a.z + a.w + b.x + b.y + b.z + b.w;
  #pragma unroll
  for (int m = 32; m >= 1; m >>= 1) s += __shfl_xor(s, m);
  const float mu = s * (1.0f / 512.0f);
  const float d0 = a.x - mu, d1 = a.y - mu, d2 = a.z - mu, d3 = a.w - mu;
  const float e0 = b.x - mu, e1 = b.y - mu, e2 = b.z - mu, e3 = b.w - mu;
  float q = d0*d0 + d1*d1 + d2*d2 + d3*d3 + e0*e0 + e1*e1 + e2*e2 + e3*e3;
  #pragma unroll
  for (int m = 32; m >= 1; m >>= 1) q += __shfl_xor(q, m);
  const float inv = rsqrtf(q * (1.0f / 512.0f) + 1e-3f);
  const float4* gr = reinterpret_cast<const float4*>(g);
  const float4* br = reinterpret_cast<const float4*>(be);
  const float4 g0 = gr[lane], g1 = gr[lane + 64];
  const float4 h0 = br[lane], h1 = br[lane + 64];
  ushort4 o0, o1;
  o0.x = f2bf(d0 * inv * g0.x + h0.x);
  o0.y = f2bf(d1 * inv * g0.y + h0.y);
  o0.z = f2bf(d2 * inv * g0.z + h0.z);
  o0.w = f2bf(d3 * inv * g0.w + h0.w);
  o1.x = f2bf(e0 * inv * g1.x + h1.x);
  o1.y = f2bf(e1 * inv * g1.y + h1.y);
  o1.z = f2bf(e2 * inv * g1.z + h1.z);
  o1.w = f2bf(e3 * inv * g1.w + h1.w);
  *reinterpret_cast<ushort4*>(y + (size_t)wid * 512 + lane * 4) = o0;
  *reinterpret_cast<ushort4*>(y + (size_t)wid * 512 + (lane + 64) * 4) = o1;
}

// ---------------------------------------------------------------- GEMM 128x128, BK=32, dbuf 2-phase
// LDS [128][32] per buffer; phys granule p of row r holds logical p^((r>>1)&3).
template<bool RELU, bool HASBIAS, bool HASRES, bool OUTBF>
__global__ __launch_bounds__(256) void gemm128_k(
    const unsigned short* __restrict__ A,
    const unsigned short* __restrict__ Wt,
    const float* __restrict__ bias,
    const float* __restrict__ res,
    void* __restrict__ outp, int M, int N, int K)
{
  __shared__ __align__(16) unsigned short As0[4096], Bs0[4096];
  __shared__ __align__(16) unsigned short As1[4096], Bs1[4096];
  const int t = threadIdx.x;
  // XCD-aware bijective remap (nwg % 8 == 0): same-row blocks -> same XCD
  const int nwg = gridDim.x * gridDim.y;
  const int bid = blockIdx.y * gridDim.x + blockIdx.x;
  const int nid = (bid & 7) * (nwg >> 3) + (bid >> 3);
  const int bx = nid % gridDim.x, by = nid / gridDim.x;
  const int m0 = by * 128, n0 = bx * 128;
  const int w = t >> 6, lane = t & 63, llo = lane & 15, lhi = lane >> 4;
  const int wr = w >> 1, wc = w & 1;

  // staging: chunk c in {t, 256+t}: row c>>2, phys granule c&3,
  // source granule sg = (c&3)^((c>>3)&3) (same value for both passes)
  const int sr = t >> 2, sg = (t & 3) ^ ((t >> 3) & 3);
  const unsigned short* pa = &A[(size_t)(m0 + sr) * K + sg * 8];
  const unsigned short* pb = &Wt[(size_t)(n0 + sr) * K + sg * 8];

#define GSTAGE128(AsX, BsX, koff) do { \
    gl16(pa + (koff), &AsX[t * 8]); \
    gl16(pa + (size_t)64 * K + (koff), &AsX[2048 + t * 8]); \
    gl16(pb + (koff), &BsX[t * 8]); \
    gl16(pb + (size_t)64 * K + (koff), &BsX[2048 + t * 8]); \
  } while (0)

  const int pgo = (lhi ^ ((llo >> 1) & 3)) * 8;   // swizzled 16B-granule offset

#define GCOMP128(AsX, BsX) do { \
    bf16x8 af[4], bfr[4]; \
    _Pragma("unroll") \
    for (int f = 0; f < 4; f++) { \
      af[f]  = *reinterpret_cast<const bf16x8*>(&AsX[(wr * 64 + f * 16 + llo) * 32 + pgo]); \
      bfr[f] = *reinterpret_cast<const bf16x8*>(&BsX[(wc * 64 + f * 16 + llo) * 32 + pgo]); \
    } \
    _Pragma("unroll") \
    for (int fi = 0; fi < 4; fi++) \
      _Pragma("unroll") \
      for (int fj = 0; fj < 4; fj++) \
        acc[fi][fj] = __builtin_amdgcn_mfma_f32_16x16x32_bf16(af[fi], bfr[fj], acc[fi][fj], 0, 0, 0); \
  } while (0)

  f32x4 acc[4][4] = {};
  GSTAGE128(As0, Bs0, 0);
  for (int k0 = 0; k0 < K; k0 += 64) {
    __syncthreads();
    GSTAGE128(As1, Bs1, k0 + 32);
    GCOMP128(As0, Bs0);
    __syncthreads();
    if (k0 + 64 < K) GSTAGE128(As0, Bs0, k0 + 64);
    GCOMP128(As1, Bs1);
  }
#undef GSTAGE128
#undef GCOMP128

  const int row0 = m0 + wr * 64, col0 = n0 + wc * 64;
  #pragma unroll
  for (int fi = 0; fi < 4; fi++)
    #pragma unroll
    for (int fj = 0; fj < 4; fj++)
      #pragma unroll
      for (int i = 0; i < 4; i++) {
        const int row = row0 + fi * 16 + lhi * 4 + i;
        const int col = col0 + fj * 16 + llo;
        float v = acc[fi][fj][i];
        if (HASBIAS) v += bias[col];
        if (HASRES)  v += res[(size_t)row * N + col];
        if (RELU)    v = fmaxf(v, 0.0f);
        if (OUTBF) ((unsigned short*)outp)[(size_t)row * N + col] = f2bf(v);
        else       ((float*)outp)[(size_t)row * N + col] = v;
      }
}

// ---------------------------------------------------------------- GEMM 64x128, BK=32, dbuf 2-phase
template<bool RELU, bool HASBIAS, bool HASRES, bool OUTBF>
__global__ __launch_bounds__(256) void gemm64_k(
    const unsigned short* __restrict__ A,
    const unsigned short* __restrict__ Wt,
    const float* __restrict__ bias,
    const float* __restrict__ res,
    void* __restrict__ outp, int M, int N, int K)
{
  __shared__ __align__(16) unsigned short As0[2048], Bs0[4096];
  __shared__ __align__(16) unsigned short As1[2048], Bs1[4096];
  const int t = threadIdx.x;
  const int nwg = gridDim.x * gridDim.y;
  const int bid = blockIdx.y * gridDim.x + blockIdx.x;
  const int nid = (bid & 7) * (nwg >> 3) + (bid >> 3);
  const int bx = nid % gridDim.x, by = nid / gridDim.x;
  const int m0 = by * 64, n0 = bx * 128;
  const int w = t >> 6, lane = t & 63, llo = lane & 15, lhi = lane >> 4;
  const int wr = w >> 1, wc = w & 1;

  const int sr = t >> 2, sg = (t & 3) ^ ((t >> 3) & 3);
  const unsigned short* pa = &A[(size_t)(m0 + sr) * K + sg * 8];
  const unsigned short* pb = &Wt[(size_t)(n0 + sr) * K + sg * 8];

#define GSTAGE64(AsX, BsX, koff) do { \
    gl16(pa + (koff), &AsX[t * 8]); \
    gl16(pb + (koff), &BsX[t * 8]); \
    gl16(pb + (size_t)64 * K + (koff), &BsX[2048 + t * 8]); \
  } while (0)

  const int pgo = (lhi ^ ((llo >> 1) & 3)) * 8;

#define GCOMP64(AsX, BsX) do { \
    bf16x8 af[2], bfr[4]; \
    _Pragma("unroll") \
    for (int f = 0; f < 2; f++) \
      af[f] = *reinterpret_cast<const bf16x8*>(&AsX[(wr * 32 + f * 16 + llo) * 32 + pgo]); \
    _Pragma("unroll") \
    for (int f = 0; f < 4; f++) \
      bfr[f] = *reinterpret_cast<const bf16x8*>(&BsX[(wc * 64 + f * 16 + llo) * 32 + pgo]); \
    _Pragma("unroll") \
    for (int fi = 0; fi < 2; fi++) \
      _Pragma("unroll") \
      for (int fj = 0; fj < 4; fj++) \
        acc[fi][fj] = __builtin_amdgcn_mfma_f32_16x16x32_bf16(af[fi], bfr[fj], acc[fi][fj], 0, 0, 0); \
  } while (0)

  f32x4 acc[2][4] = {};
  GSTAGE64(As0, Bs0, 0);
  for (int k0 = 0; k0 < K; k0 += 64) {
    __syncthreads();
    GSTAGE64(As1, Bs1, k0 + 32);
    GCOMP64(As0, Bs0);
    __syncthreads();
    if (k0 + 64 < K) GSTAGE64(As0, Bs0, k0 + 64);
    GCOMP64(As1, Bs1);
  }
#undef GSTAGE64
#undef GCOMP64

  const int row0 = m0 + wr * 32, col0 = n0 + wc * 64;
  #pragma unroll
  for (int fi = 0; fi < 2; fi++)
    #pragma unroll
    for (int fj = 0; fj < 4; fj++)
      #pragma unroll
      for (int i = 0; i < 4; i++) {
        const int row = row0 + fi * 16 + lhi * 4 + i;
        const int col = col0 + fj * 16 + llo;
        float v = acc[fi][fj][i];
        if (HASBIAS) v += bias[col];
        if (HASRES)  v += res[(size_t)row * N + col];
        if (RELU)    v = fmaxf(v, 0.0f);
        if (OUTBF) ((unsigned short*)outp)[(size_t)row * N + col] = f2bf(v);
        else       ((float*)outp)[(size_t)row * N + col] = v;
      }
}

// ---------------------------------------------------------------- V transpose
__global__ __launch_bounds__(256) void vtrans_k(
    const unsigned short* __restrict__ QKV, unsigned short* __restrict__ VT)
{
  __shared__ unsigned short tile[64][66];
  const int kt = blockIdx.x, bh = blockIdx.y;
  const int bb = bh >> 3, h = bh & 7;
  const int t = threadIdx.x;
  const int r = t >> 2, c0 = (t & 3) * 16;
  const unsigned short* src = &QKV[((size_t)bb * SEQ + kt * 64 + r) * QKVW + 1024 + h * 64 + c0];
  *reinterpret_cast<uint4*>(&tile[r][c0])     = *reinterpret_cast<const uint4*>(src);
  *reinterpret_cast<uint4*>(&tile[r][c0 + 8]) = *reinterpret_cast<const uint4*>(src + 8);
  __syncthreads();
  const int dv = t >> 2, kv0 = (t & 3) * 16;
  unsigned short tmp[16];
  #pragma unroll
  for (int j = 0; j < 16; j++) tmp[j] = tile[kv0 + j][dv];
  ushort4 o0, o1, o2, o3;
  o0.x = tmp[0];  o0.y = tmp[1];  o0.z = tmp[2];  o0.w = tmp[3];
  o1.x = tmp[4];  o1.y = tmp[5];  o1.z = tmp[6];  o1.w = tmp[7];
  o2.x = tmp[8];  o2.y = tmp[9];  o2.z = tmp[10]; o2.w = tmp[11];
  o3.x = tmp[12]; o3.y = tmp[13]; o3.z = tmp[14]; o3.w = tmp[15];
  unsigned short* dst = &VT[((size_t)bh * 64 + dv) * SEQ + kt * 64 + kv0];
  *reinterpret_cast<ushort4*>(dst)      = o0;
  *reinterpret_cast<ushort4*>(dst + 4)  = o1;
  *reinterpret_cast<ushort4*>(dst + 8)  = o2;
  *reinterpret_cast<ushort4*>(dst + 12) = o3;
}

// ---------------------------------------------------------------- attention
// block = (qt 0..15, h, b); 4 waves x 16 q-rows; kv tiles of 64; K/V dbuf
// 2-phase (stage t+1 before compute t, one barrier per tile). Static-max
// log2-domain softmax (Q pre-scaled by 0.125*log2e, acc init -16).
__global__ __launch_bounds__(256) void attn_k(
    const unsigned short* __restrict__ QKV,   // [8192][1536]
    const unsigned short* __restrict__ VT,    // [bh][64][1024]
    unsigned short* __restrict__ Zb)          // [8192][512]
{
  __shared__ __align__(16) unsigned short Ks0[4096], Vs0[4096];
  __shared__ __align__(16) unsigned short Ks1[4096], Vs1[4096];
  __shared__ __align__(16) unsigned short Ps[4096];   // 4 waves x 1024

  const int t = threadIdx.x;
  const int qt = blockIdx.x, h = blockIdx.y, bb = blockIdx.z;
  const int w = t >> 6, lane = t & 63, llo = lane & 15, lhi = lane >> 4;
  const size_t rowb = (size_t)bb * SEQ;
  const int kcol = 512 + h * 64;
  const size_t vtb = (size_t)(bb * 8 + h) * 64 * SEQ;

  // hoist Q fragments (0.125*log2e folded into Wq)
  bf16x8 aq[2];
  #pragma unroll
  for (int ds = 0; ds < 2; ds++)
    aq[ds] = *reinterpret_cast<const bf16x8*>(
        &QKV[(rowb + qt * 64 + w * 16 + llo) * QKVW + h * 64 + ds * 32 + lhi * 8]);

  // frag-major staging sources (chunk c = iss*256 + t)
  const int cA = t, cB = 256 + t;
  const int gA = cA >> 6, lA = cA & 63, gB = cB >> 6, lB = cB & 63;
  const unsigned short* kpA = &QKV[(rowb + (gA >> 1) * 16 + (lA & 15)) * QKVW + kcol + (gA & 1) * 32 + (lA >> 4) * 8];
  const unsigned short* kpB = &QKV[(rowb + (gB >> 1) * 16 + (lB & 15)) * QKVW + kcol + (gB & 1) * 32 + (lB >> 4) * 8];
  const unsigned short* vpA = &VT[vtb + (size_t)((gA >> 1) * 16 + (lA & 15)) * SEQ + (gA & 1) * 32 + (lA >> 4) * 8];
  const unsigned short* vpB = &VT[vtb + (size_t)((gB >> 1) * 16 + (lB & 15)) * SEQ + (gB & 1) * 32 + (lB >> 4) * 8];

#define ASTAGE(KsX, VsX, ktt) do { \
    gl16(kpA + (size_t)(ktt) * 64 * QKVW, &KsX[cA * 8]); \
    gl16(kpB + (size_t)(ktt) * 64 * QKVW, &KsX[cB * 8]); \
    gl16(vpA + (ktt) * 64, &VsX[cA * 8]); \
    gl16(vpB + (ktt) * 64, &VsX[cB * 8]); \
  } while (0)

#define ACOMP(KsX, VsX) do { \
    f32x4 s_[4]; \
    _Pragma("unroll") \
    for (int fj = 0; fj < 4; fj++) \
      _Pragma("unroll") \
      for (int i = 0; i < 4; i++) s_[fj][i] = -16.0f; \
    _Pragma("unroll") \
    for (int ds = 0; ds < 2; ds++) \
      _Pragma("unroll") \
      for (int fj = 0; fj < 4; fj++) { \
        bf16x8 bk = *reinterpret_cast<const bf16x8*>(&KsX[((fj * 2 + ds) * 64 + lane) * 8]); \
        s_[fj] = __builtin_amdgcn_mfma_f32_16x16x32_bf16(aq[ds], bk, s_[fj], 0, 0, 0); \
      } \
    _Pragma("unroll") \
    for (int fj = 0; fj < 4; fj++) \
      _Pragma("unroll") \
      for (int i = 0; i < 4; i++) { \
        const float p = exp2_fast(s_[fj][i]); \
        l_[i] += p; \
        Ps[w * 1024 + (fj >> 1) * 512 + ((fj & 1) * 2 + (llo >> 3)) * 128 \
           + (lhi * 4 + i) * 8 + (llo & 7)] = f2bf(p); \
      } \
    _Pragma("unroll") \
    for (int ks = 0; ks < 2; ks++) { \
      bf16x8 ap = *reinterpret_cast<const bf16x8*>(&Ps[w * 1024 + (ks * 64 + lane) * 8]); \
      _Pragma("unroll") \
      for (int fo = 0; fo < 4; fo++) { \
        bf16x8 bv = *reinterpret_cast<const bf16x8*>(&VsX[((fo * 2 + ks) * 64 + lane) * 8]); \
        o_[fo] = __builtin_amdgcn_mfma_f32_16x16x32_bf16(ap, bv, o_[fo], 0, 0, 0); \
      } \
    } \
  } while (0)

  float l_[4] = {0.0f, 0.0f, 0.0f, 0.0f};
  f32x4 o_[4] = {};

  ASTAGE(Ks0, Vs0, 0);
  for (int kt = 0; kt < 16; kt += 2) {
    __syncthreads();
    ASTAGE(Ks1, Vs1, kt + 1);
    ACOMP(Ks0, Vs0);
    __syncthreads();
    if (kt + 2 < 16) ASTAGE(Ks0, Vs0, kt + 2);
    ACOMP(Ks1, Vs1);
  }
#undef ASTAGE
#undef ACOMP

  // single end-of-loop l reduction across the 16 column-lanes
  #pragma unroll
  for (int i = 0; i < 4; i++) {
    l_[i] += __shfl_xor(l_[i], 1);
    l_[i] += __shfl_xor(l_[i], 2);
    l_[i] += __shfl_xor(l_[i], 4);
    l_[i] += __shfl_xor(l_[i], 8);
  }

  #pragma unroll
  for (int fo = 0; fo < 4; fo++)
    #pragma unroll
    for (int i = 0; i < 4; i++) {
      const float v = o_[fo][i] / l_[i];
      Zb[(rowb + qt * 64 + w * 16 + lhi * 4 + i) * 512 + h * 64 + fo * 16 + llo] = f2bf(v);
    }
}

// ---------------------------------------------------------------- driver
extern "C" void kernel_launch(void* const* d_in, const int* in_sizes, int n_in,
                              void* d_out, int out_size, void* d_ws, size_t ws_size,
                              hipStream_t stream)
{
  const float* x   = (const float*)d_in[0];
  const float* Wq  = (const float*)d_in[1];
  const float* Wk  = (const float*)d_in[2];
  const float* Wv  = (const float*)d_in[3];
  const float* Wo  = (const float*)d_in[4];
  const float* W1  = (const float*)d_in[5];
  const float* b1  = (const float*)d_in[6];
  const float* W2  = (const float*)d_in[7];
  const float* b2  = (const float*)d_in[8];
  const float* ga  = (const float*)d_in[9];
  const float* ba  = (const float*)d_in[10];
  const float* gf  = (const float*)d_in[11];
  const float* bfn = (const float*)d_in[12];
  float* out = (float*)d_out;

  char* p = (char*)d_ws;
  auto alloc = [&](size_t bytes) { void* r = (void*)p; p += (bytes + 255) & ~(size_t)255; return r; };
  float* E0 = (float*)alloc((size_t)ROWS * 512 * 4);
  float* E1 = (float*)alloc((size_t)ROWS * 512 * 4);
  unsigned short* Ybf   = (unsigned short*)alloc((size_t)ROWS * 512 * 2);
  unsigned short* QKVbf = (unsigned short*)alloc((size_t)ROWS * QKVW * 2);
  unsigned short* H1bf  = (unsigned short*)alloc((size_t)ROWS * 2048 * 2);
  unsigned short* VT    = H1bf;   // aliases front 8MB of H1bf (disjoint in time)
  unsigned short* WtQKV = (unsigned short*)alloc(6ull * QKVW * 512 * 2);
  unsigned short* WtO   = (unsigned short*)alloc(6ull * 512 * 512 * 2);
  unsigned short* Wt1   = (unsigned short*)alloc(6ull * 2048 * 512 * 2);
  unsigned short* Wt2   = (unsigned short*)alloc(6ull * 512 * 2048 * 2);
  unsigned short* Zbf   = Ybf;

  // weight prep (Wq carries softmax scale AND log2e for exp2-domain softmax)
  const float qscale = 0.125f * 1.44269504f;
  transpose_cast_k<<<dim3(16, 16, 6), 256, 0, stream>>>(Wq, WtQKV,          512, 512,  QKVW * 512, qscale);
  transpose_cast_k<<<dim3(16, 16, 6), 256, 0, stream>>>(Wk, WtQKV + 262144, 512, 512,  QKVW * 512, 1.0f);
  transpose_cast_k<<<dim3(16, 16, 6), 256, 0, stream>>>(Wv, WtQKV + 524288, 512, 512,  QKVW * 512, 1.0f);
  transpose_cast_k<<<dim3(16, 16, 6), 256, 0, stream>>>(Wo, WtO,            512, 512,  262144,     1.0f);
  transpose_cast_k<<<dim3(64, 16, 6), 256, 0, stream>>>(W1, Wt1,            512, 2048, 1048576,    1.0f);
  transpose_cast_k<<<dim3(16, 64, 6), 256, 0, stream>>>(W2, Wt2,            2048, 512, 1048576,    1.0f);

  for (int l = 0; l < 6; l++) {
    const float* enc = (l == 0) ? x : E0;
    // pre-LN attention
    ln_k<<<2048, 256, 0, stream>>>(enc, ga + l * 512, ba + l * 512, Ybf, ROWS);
    gemm128_k<false, false, false, true><<<dim3(12, 64), 256, 0, stream>>>(
        Ybf, WtQKV + (size_t)l * QKVW * 512, nullptr, nullptr, QKVbf, ROWS, QKVW, 512);
    vtrans_k<<<dim3(16, 64), 256, 0, stream>>>(QKVbf, VT);
    attn_k<<<dim3(16, 8, 8), 256, 0, stream>>>(QKVbf, VT, Zbf);
    gemm64_k<false, false, true, false><<<dim3(4, 128), 256, 0, stream>>>(
        Zbf, WtO + (size_t)l * 262144, nullptr, enc, E1, ROWS, 512, 512);
    // pre-LN FFN
    ln_k<<<2048, 256, 0, stream>>>(E1, gf + l * 512, bfn + l * 512, Ybf, ROWS);
    gemm128_k<true, true, false, true><<<dim3(16, 64), 256, 0, stream>>>(
        Ybf, Wt1 + (size_t)l * 1048576, b1 + l * 2048, nullptr, H1bf, ROWS, 2048, 512);
    gemm64_k<false, true, true, false><<<dim3(4, 128), 256, 0, stream>>>(
        H1bf, Wt2 + (size_t)l * 1048576, b2 + l * 512, E1, (l == 5) ? out : E0,
        ROWS, 512, 2048);
  }
}